// Round 6
// baseline (751.094 us; speedup 1.0000x reference)
//
#include <hip/hip_runtime.h>

typedef unsigned short ushort;
typedef unsigned int uint;
typedef __attribute__((ext_vector_type(8))) short short8;
typedef __attribute__((ext_vector_type(4))) float float4v;

#define DEV __device__ __forceinline__

DEV float b2f(ushort u) {
    union { uint i; float f; } v; v.i = ((uint)u) << 16; return v.f;
}
DEV ushort f2b(float f) {
    union { float f; uint i; } v; v.f = f;
    uint x = v.i;
    uint r = x + 0x7fffu + ((x >> 16) & 1u);
    return (ushort)(r >> 16);
}
DEV float leaky(float x, float s) { return x >= 0.f ? x : s * x; }

DEV void gload16(const void* g, void* l) {
    __builtin_amdgcn_global_load_lds((const __attribute__((address_space(1))) void*)g,
                                     (__attribute__((address_space(3))) void*)l, 16, 0, 0);
}

// ---------------- convert (+local sniff, +zero slice, +flag write) ----------------
struct ConvArgs {
    const void* s[37];
    float* d[37];
    int n[37];
};

__global__ __launch_bounds__(256) void convert_kernel(ConvArgs a, const ushort* __restrict__ x0,
                                                      int* __restrict__ flag) {
    __shared__ int sfp32;
    int tid = threadIdx.x;
    if (tid < 64) {
        int cnt = 0;
        for (int j = 0; j < 8; j++) {
            ushort u = x0[(tid * 8 + j) * 2];
            int e = (u >> 7) & 0xFF;
            if (e >= 100 && e <= 140) cnt++;
        }
#pragma unroll
        for (int m = 1; m < 64; m <<= 1) cnt += __shfl_xor(cnt, m, 64);
        if (tid == 0) sfp32 = (cnt < 256) ? 1 : 0;
    }
    __syncthreads();
    bool fp32 = (sfp32 != 0);
    if (blockIdx.x == 0 && blockIdx.y == 0 && tid == 0) *flag = fp32 ? 1 : 0;

    int ai = blockIdx.y;
    int n = a.n[ai];
    const void* s = a.s[ai];
    float* d = a.d[ai];
    int stride = gridDim.x * blockDim.x;
    if (s == nullptr) {
        for (int i = blockIdx.x * blockDim.x + tid; i < n; i += stride) d[i] = 0.f;
    } else {
        for (int i = blockIdx.x * blockDim.x + tid; i < n; i += stride)
            d[i] = fp32 ? ((const float*)s)[i] : b2f(((const ushort*)s)[i]);
    }
}

// ---------------- pack weights to bf16 [K/8][N][8] + fold-in prep_elr (y==5) ----------------
struct PackArgs { const float* W; ushort* O; int K; int N; };
struct Pack5 {
    PackArgs m[5];
    const float *W1, *al1, *ar1;
    float *wal, *war;
};

__global__ __launch_bounds__(256) void pack5_kernel(Pack5 pa) {
    int mi = blockIdx.y;
    if (mi == 5) {
        // prep: wal[k][h] = sum_d W1[k][h*64+d]*al1[h][d]  (el/er linear in h)
        if (blockIdx.x == 0 && threadIdx.x < 20) {
            int t = threadIdx.x;
            int k = t >> 2, h = t & 3;
            float sl = 0.f, sr = 0.f;
            for (int d = 0; d < 64; d++) {
                float w = pa.W1[k * 256 + h * 64 + d];
                sl += w * pa.al1[h * 64 + d];
                sr += w * pa.ar1[h * 64 + d];
            }
            pa.wal[t] = sl;
            pa.war[t] = sr;
        }
        return;
    }
    const float* __restrict__ W = pa.m[mi].W;
    ushort* __restrict__ O = pa.m[mi].O;
    int K = pa.m[mi].K, N = pa.m[mi].N;
    int G = (K >> 3) * N;
    for (int gi = blockIdx.x * 256 + threadIdx.x; gi < G; gi += gridDim.x * 256) {
        int kb = gi / N;
        int n = gi - kb * N;
        const float* wp = W + (size_t)(kb * 8) * N + n;
        uint4 pk;
        pk.x = (uint)f2b(wp[0]) | ((uint)f2b(wp[N]) << 16);
        pk.y = (uint)f2b(wp[2 * N]) | ((uint)f2b(wp[3 * N]) << 16);
        pk.z = (uint)f2b(wp[4 * N]) | ((uint)f2b(wp[5 * N]) << 16);
        pk.w = (uint)f2b(wp[6 * N]) | ((uint)f2b(wp[7 * N]) << 16);
        *(uint4*)(O + (size_t)gi * 8) = pk;
    }
}

// ---------------- CSR build (patch+mesh merged) ----------------
__global__ __launch_bounds__(256) void hist_both(const int* __restrict__ dstP, int* __restrict__ cntP, int EPc,
                                                 const int* __restrict__ dstM, int* __restrict__ cntM, int EMc,
                                                 int PB) {
    bool patch = (int)blockIdx.x < PB;
    const int* dst = patch ? dstP : dstM;
    int* cnt = patch ? cntP : cntM;
    int E = patch ? EPc : EMc;
    int nb = patch ? PB : gridDim.x - PB;
    int b = patch ? blockIdx.x : blockIdx.x - PB;
    int stride = nb * blockDim.x;
    for (int i = b * blockDim.x + threadIdx.x; i < E; i += stride)
        atomicAdd(&cnt[dst[i]], 1);
}

__global__ __launch_bounds__(256) void scan_both(const int* __restrict__ cntP, int* __restrict__ offP,
                                                 int* __restrict__ bsumP, int nP, int SBP,
                                                 const int* __restrict__ cntM, int* __restrict__ offM,
                                                 int* __restrict__ bsumM, int nM) {
    __shared__ int ls[256];
    bool patch = (int)blockIdx.x < SBP;
    const int* cnt = patch ? cntP : cntM;
    int* off = patch ? offP : offM;
    int* bsum = patch ? bsumP : bsumM;
    int n = patch ? nP : nM;
    int b = patch ? blockIdx.x : blockIdx.x - SBP;
    int t = threadIdx.x;
    int base = b * 2048 + t * 8;
    int v[8];
    int s = 0;
#pragma unroll
    for (int i = 0; i < 8; i++) {
        int idx = base + i;
        v[i] = idx < n ? cnt[idx] : 0;
        s += v[i];
    }
    ls[t] = s;
    __syncthreads();
#pragma unroll
    for (int d = 1; d < 256; d <<= 1) {
        int add = (t >= d) ? ls[t - d] : 0;
        __syncthreads();
        ls[t] += add;
        __syncthreads();
    }
    int run = ls[t] - s;
#pragma unroll
    for (int i = 0; i < 8; i++) {
        int idx = base + i;
        if (idx < n) off[idx] = run;
        run += v[i];
    }
    if (t == 255) bsum[b] = ls[255];
}

__global__ __launch_bounds__(256) void fixup_both(const int* __restrict__ bsumP, int* __restrict__ offP,
                                                  int nP, int SBP,
                                                  const int* __restrict__ bsumM, int* __restrict__ offM,
                                                  int nM, int SBM) {
    bool patch = (int)blockIdx.x < SBP;
    const int* bsum = patch ? bsumP : bsumM;
    int* off = patch ? offP : offM;
    int n = patch ? nP : nM;
    int nb = patch ? SBP : SBM;
    int b = patch ? blockIdx.x : blockIdx.x - SBP;
    int t = threadIdx.x;
    int base = 0;
    for (int i = 0; i < b; i++) base += bsum[i];
    int idx0 = b * 2048 + t * 8;
    if (base != 0) {
#pragma unroll
        for (int i = 0; i < 8; i++) {
            int idx = idx0 + i;
            if (idx < n) off[idx] += base;
        }
    }
    if (b == nb - 1 && t == 255) off[n] = base + bsum[b];
}

__global__ __launch_bounds__(256) void scatter_both(const int* __restrict__ srcP, const int* __restrict__ dstP,
                                                    const int* __restrict__ offP, int* __restrict__ curP,
                                                    int* __restrict__ csrP, int EPc,
                                                    const int* __restrict__ srcM, const int* __restrict__ dstM,
                                                    const int* __restrict__ offM, int* __restrict__ curM,
                                                    int* __restrict__ csrM, int EMc, int PB) {
    bool patch = (int)blockIdx.x < PB;
    const int* src = patch ? srcP : srcM;
    const int* dst = patch ? dstP : dstM;
    const int* off = patch ? offP : offM;
    int* cursor = patch ? curP : curM;
    int* csr = patch ? csrP : csrM;
    int E = patch ? EPc : EMc;
    int nb = patch ? PB : gridDim.x - PB;
    int b = patch ? blockIdx.x : blockIdx.x - PB;
    int stride = nb * blockDim.x;
    for (int i = b * blockDim.x + threadIdx.x; i < E; i += stride) {
        int d = dst[i];
        int pos = off[d] + atomicAdd(&cursor[d], 1);
        csr[pos] = src[i];
    }
}

// ---------------- layer-1: el/er via precomputed 5x4 wal/war (one thread per node) ----------------
__global__ __launch_bounds__(256) void proj1b_kernel(const float* __restrict__ x,
                                                     const float* __restrict__ wal,
                                                     const float* __restrict__ war,
                                                     float* __restrict__ el,
                                                     float* __restrict__ er, int Nn) {
    int n = blockIdx.x * 256 + threadIdx.x;
    if (n >= Nn) return;
    float xv[5];
#pragma unroll
    for (int k = 0; k < 5; k++) xv[k] = x[n * 5 + k];
    float l0 = 0.f, l1 = 0.f, l2 = 0.f, l3 = 0.f;
    float r0 = 0.f, r1 = 0.f, r2 = 0.f, r3 = 0.f;
#pragma unroll
    for (int k = 0; k < 5; k++) {
        float xk = xv[k];
        l0 += xk * wal[k * 4 + 0];
        l1 += xk * wal[k * 4 + 1];
        l2 += xk * wal[k * 4 + 2];
        l3 += xk * wal[k * 4 + 3];
        r0 += xk * war[k * 4 + 0];
        r1 += xk * war[k * 4 + 1];
        r2 += xk * war[k * 4 + 2];
        r3 += xk * war[k * 4 + 3];
    }
    *(float4*)(el + n * 4) = make_float4(l0, l1, l2, l3);
    *(float4*)(er + n * 4) = make_float4(r0, r1, r2, r3);
}

// ---------------- patch layer-1 aggregation: work-stealing tiles, register colstats ----------------
__global__ __launch_bounds__(256, 4) void aggr1_fly_kernel(const float* __restrict__ x,
                                                           const float* __restrict__ W,
                                                           const float* __restrict__ el,
                                                           const float* __restrict__ er,
                                                           const int* __restrict__ off,
                                                           const int* __restrict__ csr,
                                                           float* __restrict__ out,
                                                           float* __restrict__ cstat,
                                                           int* __restrict__ ctr,
                                                           int ntiles, int Nn) {
    __shared__ float s1m[4][256];
    __shared__ float s1q[4][256];
    __shared__ int stile;
    int wid = threadIdx.x >> 6;
    int lane = threadIdx.x & 63;
    int grp = lane / 20;          // 0..3 (grp 3 idle for edge work)
    int gl = lane - grp * 20;
    int h_ = gl / 5, k_ = gl - h_ * 5;  // h_ 0..3, k_ 0..4
    int c0 = lane * 4;
    int myhead = lane >> 4;
    float w0[5], w1[5], w2[5], w3[5];
#pragma unroll
    for (int k = 0; k < 5; k++) {
        float4 wv = *(const float4*)(W + k * 256 + c0);
        w0[k] = wv.x; w1[k] = wv.y; w2[k] = wv.z; w3[k] = wv.w;
    }
    float ls0 = 0.f, ls1 = 0.f, ls2 = 0.f, ls3 = 0.f;
    float lq0 = 0.f, lq1 = 0.f, lq2 = 0.f, lq3 = 0.f;

    for (;;) {
        if (threadIdx.x == 0) stile = atomicAdd(ctr, 1);
        __syncthreads();
        int tile = stile;
        if (tile >= ntiles) break;   // block-uniform
        int dbase = tile * 12 + wid * 3;
        int d = dbase + grp;
        bool accl = (grp < 3) && (d < Nn);
        int dd = accl ? d : 0;
        float erd = accl ? er[dd * 4 + h_] : 0.f;
        float acc = 0.f, sh = 0.f;
        int e = accl ? off[dd] : 0;
        int e1 = accl ? off[dd + 1] : 0;
#define A1_ACC(XV, EV)                                  \
    {                                                   \
        float e0_ = (EV) + erd;                         \
        e0_ = e0_ >= 0.f ? e0_ : 0.2f * e0_;            \
        float w_ = __expf(fminf(e0_, 80.f));            \
        acc += w_ * (XV);                               \
        sh += w_;                                       \
    }
        for (; e + 4 <= e1; e += 4) {
            int s0 = csr[e], s1 = csr[e + 1], s2 = csr[e + 2], s3 = csr[e + 3];
            float x0 = x[s0 * 5 + k_];
            float x1 = x[s1 * 5 + k_];
            float x2 = x[s2 * 5 + k_];
            float x3 = x[s3 * 5 + k_];
            float v0 = el[s0 * 4 + h_];
            float v1 = el[s1 * 4 + h_];
            float v2 = el[s2 * 4 + h_];
            float v3 = el[s3 * 4 + h_];
            A1_ACC(x0, v0) A1_ACC(x1, v1) A1_ACC(x2, v2) A1_ACC(x3, v3)
        }
        for (; e < e1; e++) {
            int s0 = csr[e];
            float x0 = x[s0 * 5 + k_];
            float v0 = el[s0 * 4 + h_];
            A1_ACC(x0, v0)
        }
#undef A1_ACC
        // epilogue: for each of the 3 dsts, broadcast acc[h][:] and project through W
#pragma unroll
        for (int g3 = 0; g3 < 3; g3++) {
            int dsto = dbase + g3;
            if (dsto >= Nn) break;  // wave-uniform
            float a_k[5];
#pragma unroll
            for (int k = 0; k < 5; k++) a_k[k] = __shfl(acc, g3 * 20 + myhead * 5 + k, 64);
            float s = __shfl(sh, g3 * 20 + myhead * 5, 64);
            float inv = 1.f / fmaxf(s, 1e-9f);
            float o0 = 0.f, o1 = 0.f, o2 = 0.f, o3 = 0.f;
#pragma unroll
            for (int k = 0; k < 5; k++) {
                o0 += a_k[k] * w0[k]; o1 += a_k[k] * w1[k];
                o2 += a_k[k] * w2[k]; o3 += a_k[k] * w3[k];
            }
            float4 o;
            o.x = leaky(o0 * inv, 0.01f);
            o.y = leaky(o1 * inv, 0.01f);
            o.z = leaky(o2 * inv, 0.01f);
            o.w = leaky(o3 * inv, 0.01f);
            *(float4*)(out + (size_t)dsto * 256 + c0) = o;
            ls0 += o.x; lq0 += o.x * o.x;
            ls1 += o.y; lq1 += o.y * o.y;
            ls2 += o.z; lq2 += o.z * o.z;
            ls3 += o.w; lq3 += o.w * o.w;
        }
        __syncthreads();   // all lanes read stile before next steal
    }
    // one stats flush per block: LDS reduce across waves -> 2 atomics per column
    *(float4*)&s1m[wid][c0] = make_float4(ls0, ls1, ls2, ls3);
    *(float4*)&s1q[wid][c0] = make_float4(lq0, lq1, lq2, lq3);
    __syncthreads();
    int tid = threadIdx.x;
    float ssv = 0.f, sqv = 0.f;
#pragma unroll
    for (int w8 = 0; w8 < 4; w8++) { ssv += s1m[w8][tid]; sqv += s1q[w8][tid]; }
    float* dst = cstat + (size_t)(blockIdx.x & 7) * 1024;
    atomicAdd(dst + tid, ssv);
    atomicAdd(dst + 512 + tid, sqv);
}

// ---------------- gather aggregation: work-stealing tiles, register colstats ----------------
template <int H, int LOGD, int HD>
__global__ __launch_bounds__(256, 4) void aggr4_kernel(const ushort* __restrict__ h,
                                                       const float* __restrict__ el,
                                                       const float* __restrict__ er,
                                                       const int* __restrict__ off,
                                                       const int* __restrict__ csr,
                                                       float* __restrict__ out,
                                                       float* __restrict__ cstat,
                                                       int* __restrict__ ctr,
                                                       int ntiles, int Nn,
                                                       float oslope) {
    __shared__ float ssm[8][HD];
    __shared__ float ssq[8][HD];
    __shared__ int stile;
    int wid = threadIdx.x >> 6;
    int lane = threadIdx.x & 63;
    int half = lane >> 5, hl = lane & 31;
    constexpr int NL = HD / 8;
    int myhead = (hl * 8) >> LOGD;
    float rs0 = 0.f, rs1 = 0.f, rs2 = 0.f, rs3 = 0.f;
    float rs4 = 0.f, rs5 = 0.f, rs6 = 0.f, rs7 = 0.f;
    float rq0 = 0.f, rq1 = 0.f, rq2 = 0.f, rq3 = 0.f;
    float rq4 = 0.f, rq5 = 0.f, rq6 = 0.f, rq7 = 0.f;

    for (;;) {
        if (threadIdx.x == 0) stile = atomicAdd(ctr, 1);
        __syncthreads();
        int tile = stile;
        if (tile >= ntiles) break;   // block-uniform
        int d = tile * 8 + wid * 2 + half;
        bool valid = (hl < NL) && (d < Nn);
        int dd = valid ? d : 0;
        float erd = valid ? er[dd * H + myhead] : 0.f;
        float a0 = 0.f, a1 = 0.f, a2 = 0.f, a3 = 0.f;
        float a4 = 0.f, a5 = 0.f, a6 = 0.f, a7 = 0.f, s = 0.f;
        int e = valid ? off[dd] : 0;
        int e1 = valid ? off[dd + 1] : 0;
#define A8_ACC(EV, HR)                                      \
    {                                                       \
        float ev_ = (EV) + erd;                             \
        ev_ = ev_ >= 0.f ? ev_ : 0.2f * ev_;                \
        float w_ = __expf(fminf(ev_, 80.f));                \
        a0 += w_ * b2f((ushort)(HR).x);                     \
        a1 += w_ * b2f((ushort)((HR).x >> 16));             \
        a2 += w_ * b2f((ushort)(HR).y);                     \
        a3 += w_ * b2f((ushort)((HR).y >> 16));             \
        a4 += w_ * b2f((ushort)(HR).z);                     \
        a5 += w_ * b2f((ushort)((HR).z >> 16));             \
        a6 += w_ * b2f((ushort)(HR).w);                     \
        a7 += w_ * b2f((ushort)((HR).w >> 16));             \
        s += w_;                                            \
    }
#define A8_ACCM(OK, EV, HR)                                 \
    {                                                       \
        float ev_ = (EV) + erd;                             \
        ev_ = ev_ >= 0.f ? ev_ : 0.2f * ev_;                \
        float w_ = (OK) ? __expf(fminf(ev_, 80.f)) : 0.f;   \
        a0 += w_ * b2f((ushort)(HR).x);                     \
        a1 += w_ * b2f((ushort)((HR).x >> 16));             \
        a2 += w_ * b2f((ushort)(HR).y);                     \
        a3 += w_ * b2f((ushort)((HR).y >> 16));             \
        a4 += w_ * b2f((ushort)(HR).z);                     \
        a5 += w_ * b2f((ushort)((HR).z >> 16));             \
        a6 += w_ * b2f((ushort)(HR).w);                     \
        a7 += w_ * b2f((ushort)((HR).w >> 16));             \
        s += w_;                                            \
    }
        for (; e + 4 <= e1; e += 4) {
            int s0 = csr[e], s1 = csr[e + 1], s2 = csr[e + 2], s3 = csr[e + 3];
            float e0 = el[s0 * H + myhead];
            float e1v = el[s1 * H + myhead];
            float e2v = el[s2 * H + myhead];
            float e3v = el[s3 * H + myhead];
            uint4 h0 = *(const uint4*)(h + (size_t)s0 * HD + hl * 8);
            uint4 h1 = *(const uint4*)(h + (size_t)s1 * HD + hl * 8);
            uint4 h2 = *(const uint4*)(h + (size_t)s2 * HD + hl * 8);
            uint4 h3 = *(const uint4*)(h + (size_t)s3 * HD + hl * 8);
            A8_ACC(e0, h0) A8_ACC(e1v, h1) A8_ACC(e2v, h2) A8_ACC(e3v, h3)
        }
        if (e < e1) {
            bool k1 = e + 1 < e1, k2 = e + 2 < e1, k3 = e + 3 < e1;
            int s0 = csr[e];
            int s1 = csr[k1 ? e + 1 : e];
            int s2 = csr[k2 ? e + 2 : e];
            int s3 = csr[k3 ? e + 3 : e];
            float e0 = el[s0 * H + myhead];
            float e1v = el[s1 * H + myhead];
            float e2v = el[s2 * H + myhead];
            float e3v = el[s3 * H + myhead];
            uint4 h0 = *(const uint4*)(h + (size_t)s0 * HD + hl * 8);
            uint4 h1 = *(const uint4*)(h + (size_t)s1 * HD + hl * 8);
            uint4 h2 = *(const uint4*)(h + (size_t)s2 * HD + hl * 8);
            uint4 h3 = *(const uint4*)(h + (size_t)s3 * HD + hl * 8);
            A8_ACCM(true, e0, h0) A8_ACCM(k1, e1v, h1) A8_ACCM(k2, e2v, h2) A8_ACCM(k3, e3v, h3)
        }
#undef A8_ACC
#undef A8_ACCM
        if (valid) {
            float inv = 1.f / fmaxf(s, 1e-9f);
            float o0 = leaky(a0 * inv, oslope);
            float o1 = leaky(a1 * inv, oslope);
            float o2 = leaky(a2 * inv, oslope);
            float o3 = leaky(a3 * inv, oslope);
            float o4 = leaky(a4 * inv, oslope);
            float o5 = leaky(a5 * inv, oslope);
            float o6 = leaky(a6 * inv, oslope);
            float o7 = leaky(a7 * inv, oslope);
            float* po = out + (size_t)dd * HD + hl * 8;
            *(float4*)(po) = make_float4(o0, o1, o2, o3);
            *(float4*)(po + 4) = make_float4(o4, o5, o6, o7);
            rs0 += o0; rq0 += o0 * o0;
            rs1 += o1; rq1 += o1 * o1;
            rs2 += o2; rq2 += o2 * o2;
            rs3 += o3; rq3 += o3 * o3;
            rs4 += o4; rq4 += o4 * o4;
            rs5 += o5; rq5 += o5 * o5;
            rs6 += o6; rq6 += o6 * o6;
            rs7 += o7; rq7 += o7 * o7;
        }
        __syncthreads();   // all lanes read stile before next steal
    }
    // one stats flush per block
    int r = wid * 2 + half;
    if (hl < NL) {
        int cb = hl * 8;
        *(float4*)&ssm[r][cb] = make_float4(rs0, rs1, rs2, rs3);
        *(float4*)&ssm[r][cb + 4] = make_float4(rs4, rs5, rs6, rs7);
        *(float4*)&ssq[r][cb] = make_float4(rq0, rq1, rq2, rq3);
        *(float4*)&ssq[r][cb + 4] = make_float4(rq4, rq5, rq6, rq7);
    }
    __syncthreads();
    int tid = threadIdx.x;
    if (tid < HD) {
        float sv = 0.f, qv = 0.f;
#pragma unroll
        for (int rr = 0; rr < 8; rr++) { sv += ssm[rr][tid]; qv += ssq[rr][tid]; }
        float* dst = cstat + (size_t)(blockIdx.x & 7) * 1024;
        atomicAdd(dst + tid, sv);
        atomicAdd(dst + 512 + tid, qv);
    }
}

// final GAT layer: H=2, D=32, HD=64 — 2 dst/wave + block LDS pre-reduction before atomics
__global__ __launch_bounds__(256, 4) void aggr_mean_kernel(const ushort* __restrict__ h,
                                                           const float* __restrict__ el,
                                                           const float* __restrict__ er,
                                                           const int* __restrict__ off,
                                                           const int* __restrict__ csr,
                                                           const int* __restrict__ gid,
                                                           float* __restrict__ out_sum,
                                                           float* __restrict__ out_cnt,
                                                           int Nn) {
    __shared__ float red[8][32];
    __shared__ int gids[8];
    int wid = threadIdx.x >> 6;
    int lane = threadIdx.x & 63;
    int half = lane >> 5;
    int hl = lane & 31;
    int row = wid * 2 + half;
    int d = blockIdx.x * 8 + row;
    bool valid = d < Nn;
    int dd = valid ? d : 0;
    int head = hl >> 4;  // cols 2hl, 2hl+1; head1 when hl>=16
    float erd = er[dd * 2 + head];
    float a0 = 0.f, a1 = 0.f, s = 0.f;
    int e = valid ? off[dd] : 0;
    int e1 = valid ? off[dd + 1] : 0;
#define AM_ACC(Q, V)                                        \
    {                                                       \
        float ev_ = (head ? (Q).y : (Q).x) + erd;           \
        ev_ = ev_ >= 0.f ? ev_ : 0.2f * ev_;                \
        float w_ = __expf(fminf(ev_, 80.f));                \
        a0 += w_ * b2f((ushort)(V));                        \
        a1 += w_ * b2f((ushort)((V) >> 16));                \
        s += w_;                                            \
    }
#define AM_ACCM(OK, Q, V)                                   \
    {                                                       \
        float ev_ = (head ? (Q).y : (Q).x) + erd;           \
        ev_ = ev_ >= 0.f ? ev_ : 0.2f * ev_;                \
        float w_ = (OK) ? __expf(fminf(ev_, 80.f)) : 0.f;   \
        a0 += w_ * b2f((ushort)(V));                        \
        a1 += w_ * b2f((ushort)((V) >> 16));                \
        s += w_;                                            \
    }
    for (; e + 8 <= e1; e += 8) {
        int s0 = csr[e], s1 = csr[e + 1], s2 = csr[e + 2], s3 = csr[e + 3];
        int s4 = csr[e + 4], s5 = csr[e + 5], s6 = csr[e + 6], s7 = csr[e + 7];
        float2 q0 = *(const float2*)(el + s0 * 2);
        float2 q1 = *(const float2*)(el + s1 * 2);
        float2 q2 = *(const float2*)(el + s2 * 2);
        float2 q3 = *(const float2*)(el + s3 * 2);
        float2 q4 = *(const float2*)(el + s4 * 2);
        float2 q5 = *(const float2*)(el + s5 * 2);
        float2 q6 = *(const float2*)(el + s6 * 2);
        float2 q7 = *(const float2*)(el + s7 * 2);
        uint v0 = *(const uint*)(h + (size_t)s0 * 64 + hl * 2);
        uint v1 = *(const uint*)(h + (size_t)s1 * 64 + hl * 2);
        uint v2 = *(const uint*)(h + (size_t)s2 * 64 + hl * 2);
        uint v3 = *(const uint*)(h + (size_t)s3 * 64 + hl * 2);
        uint v4 = *(const uint*)(h + (size_t)s4 * 64 + hl * 2);
        uint v5 = *(const uint*)(h + (size_t)s5 * 64 + hl * 2);
        uint v6 = *(const uint*)(h + (size_t)s6 * 64 + hl * 2);
        uint v7 = *(const uint*)(h + (size_t)s7 * 64 + hl * 2);
        AM_ACC(q0, v0) AM_ACC(q1, v1) AM_ACC(q2, v2) AM_ACC(q3, v3)
        AM_ACC(q4, v4) AM_ACC(q5, v5) AM_ACC(q6, v6) AM_ACC(q7, v7)
    }
    if (e < e1) {
        bool k1 = e + 1 < e1, k2 = e + 2 < e1, k3 = e + 3 < e1;
        bool k4 = e + 4 < e1, k5 = e + 5 < e1, k6 = e + 6 < e1, k7 = e + 7 < e1;
        int s0 = csr[e];
        int s1 = csr[k1 ? e + 1 : e];
        int s2 = csr[k2 ? e + 2 : e];
        int s3 = csr[k3 ? e + 3 : e];
        int s4 = csr[k4 ? e + 4 : e];
        int s5 = csr[k5 ? e + 5 : e];
        int s6 = csr[k6 ? e + 6 : e];
        int s7 = csr[k7 ? e + 7 : e];
        float2 q0 = *(const float2*)(el + s0 * 2);
        float2 q1 = *(const float2*)(el + s1 * 2);
        float2 q2 = *(const float2*)(el + s2 * 2);
        float2 q3 = *(const float2*)(el + s3 * 2);
        float2 q4 = *(const float2*)(el + s4 * 2);
        float2 q5 = *(const float2*)(el + s5 * 2);
        float2 q6 = *(const float2*)(el + s6 * 2);
        float2 q7 = *(const float2*)(el + s7 * 2);
        uint v0 = *(const uint*)(h + (size_t)s0 * 64 + hl * 2);
        uint v1 = *(const uint*)(h + (size_t)s1 * 64 + hl * 2);
        uint v2 = *(const uint*)(h + (size_t)s2 * 64 + hl * 2);
        uint v3 = *(const uint*)(h + (size_t)s3 * 64 + hl * 2);
        uint v4 = *(const uint*)(h + (size_t)s4 * 64 + hl * 2);
        uint v5 = *(const uint*)(h + (size_t)s5 * 64 + hl * 2);
        uint v6 = *(const uint*)(h + (size_t)s6 * 64 + hl * 2);
        uint v7 = *(const uint*)(h + (size_t)s7 * 64 + hl * 2);
        AM_ACCM(true, q0, v0) AM_ACCM(k1, q1, v1) AM_ACCM(k2, q2, v2) AM_ACCM(k3, q3, v3)
        AM_ACCM(k4, q4, v4) AM_ACCM(k5, q5, v5) AM_ACCM(k6, q6, v6) AM_ACCM(k7, q7, v7)
    }
#undef AM_ACC
#undef AM_ACCM
    float inv = 1.f / fmaxf(s, 1e-9f);
    float y0 = a0 * inv, y1 = a1 * inv;
    // head-mean: col c pairs with c+32 -> lane hl+16 within same half
    float p0 = __shfl(y0, lane + 16, 64);
    float p1 = __shfl(y1, lane + 16, 64);
    if (hl < 16) {
        red[row][2 * hl] = valid ? 0.5f * (y0 + p0) : 0.f;
        red[row][2 * hl + 1] = valid ? 0.5f * (y1 + p1) : 0.f;
        if (hl == 0) gids[row] = valid ? (gid ? gid[d] : 0) : -1;
    }
    __syncthreads();
    // block-level reduction over runs of equal gid -> few device atomics
    if (threadIdx.x < 32) {
        int c = threadIdx.x;
        float sum = 0.f;
        int cur = gids[0];
#pragma unroll
        for (int r = 0; r < 8; r++) {
            int gr = gids[r];
            if (gr != cur) {
                if (cur >= 0) atomicAdd(&out_sum[cur * 32 + c], sum);
                sum = 0.f;
                cur = gr;
            }
            if (gr >= 0) sum += red[r][c];
        }
        if (cur >= 0) atomicAdd(&out_sum[cur * 32 + c], sum);
    } else if (threadIdx.x == 32 && out_cnt) {
        float cnt = 0.f;
        int cur = gids[0];
#pragma unroll
        for (int r = 0; r < 8; r++) {
            int gr = gids[r];
            if (gr != cur) {
                if (cur >= 0) atomicAdd(&out_cnt[cur], cnt);
                cnt = 0.f;
                cur = gr;
            }
            if (gr >= 0) cnt += 1.f;
        }
        if (cur >= 0) atomicAdd(&out_cnt[cur], cnt);
    }
}

// GraphNorm apply for readout: writes d_out (per flag) + fp32 mesh input (8-copy stats)
__global__ void gnorm_apply_ro_kernel(const float* __restrict__ x,
                                      const float* __restrict__ cstat,
                                      const float* __restrict__ g,
                                      const float* __restrict__ b,
                                      const float* __restrict__ a,
                                      void* __restrict__ doutv,
                                      const int* __restrict__ flag,
                                      float* __restrict__ rof, int Nn) {
    int c = threadIdx.x;  // C = 32
    float cs = 0.f, cq = 0.f;
#pragma unroll
    for (int s8 = 0; s8 < 8; s8++) {
        cs += cstat[s8 * 1024 + c];
        cq += cstat[s8 * 1024 + 512 + c];
    }
    float invn = 1.f / (float)Nn;
    float mu = cs * invn, ex2 = cq * invn;
    float av = a[c];
    float var = ex2 - 2.f * av * mu * mu + av * av * mu * mu;
    float sc = g[c] * rsqrtf(var + 1e-5f);
    float sh = b[c] - sc * av * mu;
    bool fp32 = (*flag != 0);
    for (int r = blockIdx.x; r < Nn; r += gridDim.x) {
        int i = r * 32 + c;
        float v = x[i] * sc + sh;
        rof[i] = v;
        if (fp32) ((float*)doutv)[15 + i] = v;
        else      ((ushort*)doutv)[15 + i] = f2b(v);
    }
}

// ---------------- readout: segment-mean @ pcls + leaky (fp32 out, fused colstats) ----------------
__global__ __launch_bounds__(256) void readout_kernel(const float* __restrict__ ro_sum,
                                                      const float* __restrict__ ro_cnt,
                                                      const float* __restrict__ pcls,
                                                      float* __restrict__ ro_lin,
                                                      float* __restrict__ cstat, int NGc) {
    __shared__ float ss[32], sq[32];
    int tid = threadIdx.x;
    if (tid < 32) { ss[tid] = 0.f; sq[tid] = 0.f; }
    __syncthreads();
    int idx = blockIdx.x * 256 + tid;
    int g = idx >> 5, c = idx & 31;
    float v = 0.f;
    if (g < NGc) {
        float inv = 1.f / fmaxf(ro_cnt[g], 1.f);
        float acc = 0.f;
#pragma unroll
        for (int k = 0; k < 32; k++) acc += ro_sum[g * 32 + k] * inv * pcls[k * 32 + c];
        v = leaky(acc, 0.01f);
        ro_lin[g * 32 + c] = v;
    }
    atomicAdd(&ss[c], v);
    atomicAdd(&sq[c], v * v);
    __syncthreads();
    if (tid < 32) {
        float* dst = cstat + (size_t)(blockIdx.x & 7) * 1024;
        atomicAdd(dst + tid, ss[tid]);
        atomicAdd(dst + 512 + tid, sq[tid]);
    }
}

// ---------------- MFMA GEMM v2: C(bf16) = gnorm(A:fp32) @ B'(bf16 prepacked), fused el/er ----------------
template <int K, int N, int H, int LOGD, bool GN>
__global__ __launch_bounds__(256, 4) void gemm_bf_kernel(const float* __restrict__ A,
                                                         const ushort* __restrict__ Bc,
                                                         const float* __restrict__ csum,
                                                         const float* __restrict__ g,
                                                         const float* __restrict__ gb,
                                                         const float* __restrict__ ga,
                                                         const float* __restrict__ al,
                                                         const float* __restrict__ ar,
                                                         ushort* __restrict__ C,
                                                         float* __restrict__ el,
                                                         float* __restrict__ er, int M) {
    constexpr int NT = N / 16;
    constexpr int T = K / 32;
    constexpr int BG = 4 * N;             // B 16B-granules per 32-K chunk
    constexpr int RB = (BG + 255) / 256;  // staging rounds for B
    __shared__ __align__(16) ushort Blds[2][BG * 8];
    __shared__ float ScL[K], ShL[K];
    int tid = threadIdx.x;
    int w = tid >> 6, lane = tid & 63, q = lane >> 4, l16 = lane & 15;
    int m0 = blockIdx.x * 64;
    if constexpr (GN) {
        if (tid < K) {
            float cs = 0.f, cq = 0.f;
#pragma unroll
            for (int s8 = 0; s8 < 8; s8++) {
                cs += csum[s8 * 1024 + tid];
                cq += csum[s8 * 1024 + 512 + tid];
            }
            float invn = 1.f / (float)M;
            float mu = cs * invn, ex2 = cq * invn;
            float av = ga[tid];
            float var = ex2 - 2.f * av * mu * mu + av * av * mu * mu;
            float sc = g[tid] * rsqrtf(var + 1e-5f);
            ScL[tid] = sc;
            ShL[tid] = gb[tid] - sc * av * mu;
        }
    }
    int row = m0 + w * 16 + l16;
    const float* ap = A + (size_t)(row < M ? row : 0) * K + q * 8;

    // prologue: stage B chunk 0; preload A regs chunk 0
#pragma unroll
    for (int rb = 0; rb < RB; rb++) {
        int gidx = rb * 256 + tid;
        if (BG % 256 == 0 || gidx < BG) gload16(Bc + (size_t)gidx * 8, &Blds[0][gidx * 8]);
    }
    float4 a0 = *(const float4*)(ap);
    float4 a1 = *(const float4*)(ap + 4);
    float4v acc[NT];
#pragma unroll
    for (int nt = 0; nt < NT; nt++) acc[nt] = (float4v){0.f, 0.f, 0.f, 0.f};
    __syncthreads();  // B chunk 0 resident (+ ScL/ShL visible)

    int cur = 0;
    for (int t = 0; t < T; t++) {
        float4 n0, n1;
        bool more = (t + 1 < T);
        if (more) {
#pragma unroll
            for (int rb = 0; rb < RB; rb++) {
                int gidx = rb * 256 + tid;
                if (BG % 256 == 0 || gidx < BG)
                    gload16(Bc + (size_t)((t + 1) * BG + gidx) * 8, &Blds[cur ^ 1][gidx * 8]);
            }
            n0 = *(const float4*)(ap + (t + 1) * 32);
            n1 = *(const float4*)(ap + (t + 1) * 32 + 4);
        }
        // gnorm + pack current A fragment
        if constexpr (GN) {
            int kc = t * 32 + q * 8;
            float4 sc0 = *(const float4*)(&ScL[kc]);
            float4 sc1 = *(const float4*)(&ScL[kc + 4]);
            float4 sh0 = *(const float4*)(&ShL[kc]);
            float4 sh1 = *(const float4*)(&ShL[kc + 4]);
            a0.x = a0.x * sc0.x + sh0.x;
            a0.y = a0.y * sc0.y + sh0.y;
            a0.z = a0.z * sc0.z + sh0.z;
            a0.w = a0.w * sc0.w + sh0.w;
            a1.x = a1.x * sc1.x + sh1.x;
            a1.y = a1.y * sc1.y + sh1.y;
            a1.z = a1.z * sc1.z + sh1.z;
            a1.w = a1.w * sc1.w + sh1.w;
        }
        union { uint4 u; short8 s; } cvt;
        cvt.u.x = (uint)f2b(a0.x) | ((uint)f2b(a0.y) << 16);
        cvt.u.y = (uint)f2b(a0.z) | ((uint)f2b(a0.w) << 16);
        cvt.u.z = (uint)f2b(a1.x) | ((uint)f2b(a1.y) << 16);
        cvt.u.w = (uint)f2b(a1.z) | ((uint)f2b(a1.w) << 16);
        short8 av = cvt.s;
#pragma unroll
        for (int nt = 0; nt < NT; nt++) {
            short8 bv = *(const short8*)(&Blds[cur][(q * N + nt * 16 + l16) * 8]);
            acc[nt] = __builtin_amdgcn_mfma_f32_16x16x32_bf16(av, bv, acc[nt], 0, 0, 0);
        }
        __syncthreads();  // drains prefetch vmcnt; releases buf[cur]
        if (more) { a0 = n0; a1 = n1; }
        cur ^= 1;
    }
    // epilogue: C store (bf16) + fused el/er
    float pel[4][H], per[4][H];
#pragma unroll
    for (int i = 0; i < 4; i++)
#pragma unroll
        for (int hh = 0; hh < H; hh++) { pel[i][hh] = 0.f; per[i][hh] = 0.f; }
#pragma unroll
    for (int nt = 0; nt < NT; nt++) {
        int col = nt * 16 + l16;
        float alc = al[col], arc = ar[col];
        constexpr int HSH = LOGD - 4;
        int hh = nt >> HSH;
#pragma unroll
        for (int i = 0; i < 4; i++) {
            int orow = m0 + w * 16 + q * 4 + i;
            float v = acc[nt][i];
            if (orow < M) C[(size_t)orow * N + col] = f2b(v);
            pel[i][hh] += v * alc;
            per[i][hh] += v * arc;
        }
    }
#pragma unroll
    for (int i = 0; i < 4; i++) {
#pragma unroll
        for (int hh = 0; hh < H; hh++) {
            float vl = pel[i][hh], vr = per[i][hh];
#pragma unroll
            for (int m = 1; m < 16; m <<= 1) {
                vl += __shfl_xor(vl, m, 64);
                vr += __shfl_xor(vr, m, 64);
            }
            if (l16 == 0) {
                int orow = m0 + w * 16 + q * 4 + i;
                if (orow < M) { el[orow * H + hh] = vl; er[orow * H + hh] = vr; }
            }
        }
    }
}

// ---------------- final: node-mean @ mcls ----------------
__global__ __launch_bounds__(64) void final_kernel(const float* __restrict__ msum,
                                                   const float* __restrict__ mcls,
                                                   void* __restrict__ doutv,
                                                   const int* __restrict__ flag, int Nm) {
    int t = threadIdx.x;
    if (t < 15) {
        float inv = 1.f / (float)Nm;
        float acc = 0.f;
#pragma unroll
        for (int c = 0; c < 32; c++) acc += msum[c] * inv * mcls[c * 15 + t];
        if (*flag) ((float*)doutv)[t] = acc;
        else       ((ushort*)doutv)[t] = f2b(acc);
    }
}

extern "C" void kernel_launch(void* const* d_in, const int* in_sizes, int n_in,
                              void* d_out, int out_size, void* d_ws, size_t ws_size,
                              hipStream_t stream) {
    const int NP = 100000, NG = 2000, EP = 800000, NM = 2000, EM = 32000;

    const int* patch_src = (const int*)d_in[1];
    const int* patch_dst = (const int*)d_in[2];
    const int* patch_gid = (const int*)d_in[3];
    const int* mesh_src = (const int*)d_in[4];
    const int* mesh_dst = (const int*)d_in[5];

    char* p = (char*)d_ws;
    auto alloc = [&](size_t bytes) -> char* {
        char* r = p;
        p += (bytes + 255) & ~(size_t)255;
        return r;
    };
    char* zbase = p;
    int* cnt_p = (int*)alloc((size_t)NP * 4);
    int* cursor_p = (int*)alloc((size_t)NP * 4);
    int* cnt_m = (int*)alloc((size_t)NM * 4);
    int* cursor_m = (int*)alloc((size_t)NM * 4);
    float* ro_sum = (float*)alloc((size_t)NG * 32 * 4);
    float* ro_cnt = (float*)alloc((size_t)NG * 4);
    float* msum = (float*)alloc(32 * 4);
    float* colbuf = (float*)alloc((size_t)5 * 8 * 1024 * 4);  // stat buffers x 8 copies x (512 sum + 512 sq)
    int* wsctr = (int*)alloc(64);                              // work-steal counters (zeroed)
    size_t zbytes = (size_t)(p - zbase);
    int* flag = (int*)alloc(256);
    int* off_p = (int*)alloc((size_t)(NP + 1) * 4);
    int* off_m = (int*)alloc((size_t)(NM + 1) * 4);
    int* bsum_p = (int*)alloc(64 * 4);
    int* bsum_m = (int*)alloc(16 * 4);
    int* csr_p = (int*)alloc((size_t)EP * 4);
    int* csr_m = (int*)alloc((size_t)EM * 4);
    float* el = (float*)alloc((size_t)NP * 4 * 4);
    float* er = (float*)alloc((size_t)NP * 4 * 4);
    ushort* hbuf = (ushort*)alloc((size_t)NP * 256 * 2);   // bf16 gemm-output gather buffer
    float* gbuf = (float*)alloc((size_t)NP * 256 * 4);     // fp32 aggr output (gemm A input)
    ushort* hm = (ushort*)alloc((size_t)NM * 256 * 2);
    float* gm = (float*)alloc((size_t)NM * 256 * 4);
    float* elm = (float*)alloc((size_t)NM * 4 * 4);
    float* erm = (float*)alloc((size_t)NM * 4 * 4);
    float* ro_lin = (float*)alloc((size_t)NG * 32 * 4);
    float* ro_f = (float*)alloc((size_t)NG * 32 * 4);
    // prepacked bf16 weights [K/8][N][8]
    ushort* Bp2 = (ushort*)alloc(256 * 192 * 2);
    ushort* Bp3 = (ushort*)alloc(192 * 64 * 2);
    ushort* Bm1 = (ushort*)alloc(32 * 256 * 2);
    ushort* Bm2 = (ushort*)alloc(256 * 96 * 2);
    ushort* Bm3 = (ushort*)alloc(96 * 64 * 2);
    float* wal1 = (float*)alloc(20 * 4);
    float* war1 = (float*)alloc(20 * 4);

    ConvArgs ca;
    float* convp[36];
    int conv_idx[36];
    conv_idx[0] = 0;
    for (int i = 1; i < 36; i++) conv_idx[i] = 5 + i;
    for (int j = 0; j < 36; j++) {
        int ii = conv_idx[j];
        int n = in_sizes[ii];
        float* dd = (float*)alloc((size_t)n * 4);
        ca.s[j] = d_in[ii];
        ca.d[j] = dd;
        ca.n[j] = n;
        convp[j] = dd;
    }
    ca.s[36] = nullptr;
    ca.d[36] = (float*)zbase;
    ca.n[36] = (int)(zbytes / 4);

    const float* xf = convp[0];
    const float *pW1f = convp[1], *pal1f = convp[2], *par1f = convp[3];
    const float *pg1_gf = convp[4], *pg1_bf = convp[5], *pg1_af = convp[6];
    const float *pW2f = convp[7], *pal2f = convp[8], *par2f = convp[9];
    const float *pg2_gf = convp[10], *pg2_bf = convp[11], *pg2_af = convp[12];
    const float *pW3f = convp[13], *pal3f = convp[14], *par3f = convp[15];
    const float* pclsf = convp[16];
    const float *rn_gf = convp[17], *rn_bf2 = convp[18], *rn_af = convp[19];
    const float *mW1f = convp[20], *mal1f = convp[21], *mar1f = convp[22];
    const float *mg1_gf = convp[23], *mg1_bf = convp[24], *mg1_af = convp[25];
    const float *mW2f = convp[26], *mal2f = convp[27], *mar2f = convp[28];
    const float *mg2_gf = convp[29], *mg2_bf = convp[30], *mg2_af = convp[31];
    const float *mW3f = convp[32], *mal3f = convp[33], *mar3f = convp[34];
    const float* mclsf = convp[35];

    convert_kernel<<<dim3(16, 37), 256, 0, stream>>>(ca, (const ushort*)d_in[0], flag);

    // pack all 5 GEMM weight matrices to bf16 + prep wal/war (y==5 row)
    Pack5 p5;
    p5.m[0] = {pW2f, Bp2, 256, 192};
    p5.m[1] = {pW3f, Bp3, 192, 64};
    p5.m[2] = {mW1f, Bm1, 32, 256};
    p5.m[3] = {mW2f, Bm2, 256, 96};
    p5.m[4] = {mW3f, Bm3, 96, 64};
    p5.W1 = pW1f; p5.al1 = pal1f; p5.ar1 = par1f;
    p5.wal = wal1; p5.war = war1;
    pack5_kernel<<<dim3(48, 6), 256, 0, stream>>>(p5);

    const int SBP = (NP + 2047) / 2048, SBM = (NM + 2047) / 2048;
    hist_both<<<512 + 64, 256, 0, stream>>>(patch_dst, cnt_p, EP, mesh_dst, cnt_m, EM, 512);
    scan_both<<<SBP + SBM, 256, 0, stream>>>(cnt_p, off_p, bsum_p, NP, SBP, cnt_m, off_m, bsum_m, NM);
    fixup_both<<<SBP + SBM, 256, 0, stream>>>(bsum_p, off_p, NP, SBP, bsum_m, off_m, NM, SBM);
    scatter_both<<<512 + 64, 256, 0, stream>>>(patch_src, patch_dst, off_p, cursor_p, csr_p, EP,
                                               mesh_src, mesh_dst, off_m, cursor_m, csr_m, EM, 512);

    int t1 = (NP + 11) / 12;            // aggr1 tiles
    int g1 = t1 < 2048 ? t1 : 2048;
    int tA = (NP + 7) / 8;              // aggr4 patch tiles
    int gA = tA < 2048 ? tA : 2048;
    int tAm = (NM + 7) / 8;             // aggr4 mesh tiles
    int gP2 = (NP + 7) / 8, gM2 = (NM + 7) / 8;
    int gT = (NP + 63) / 64, gTm = (NM + 63) / 64;
    float* cb0 = colbuf + 0 * 8192;
    float* cb1 = colbuf + 1 * 8192;
    float* cb2 = colbuf + 2 * 8192;
    float* cb3 = colbuf + 3 * 8192;
    float* cb4 = colbuf + 4 * 8192;

    // ---- patch GAT layer 1 ----
    proj1b_kernel<<<(NP + 255) / 256, 256, 0, stream>>>(xf, wal1, war1, el, er, NP);
    aggr1_fly_kernel<<<g1, 256, 0, stream>>>(xf, pW1f, el, er, off_p, csr_p, gbuf, cb0,
                                             wsctr + 0, t1, NP);

    // ---- patch GAT layer 2 ----
    gemm_bf_kernel<256, 192, 3, 6, true><<<gT, 256, 0, stream>>>(
        gbuf, Bp2, cb0, pg1_gf, pg1_bf, pg1_af, pal2f, par2f, hbuf, el, er, NP);
    aggr4_kernel<3, 6, 192><<<gA, 256, 0, stream>>>(hbuf, el, er, off_p, csr_p, gbuf, cb1,
                                                    wsctr + 1, tA, NP, 0.01f);

    // ---- patch GAT layer 3 + readout ----
    gemm_bf_kernel<192, 64, 2, 5, true><<<gT, 256, 0, stream>>>(
        gbuf, Bp3, cb1, pg2_gf, pg2_bf, pg2_af, pal3f, par3f, hbuf, el, er, NP);
    aggr_mean_kernel<<<gP2, 256, 0, stream>>>(hbuf, el, er, off_p, csr_p, patch_gid,
                                              ro_sum, ro_cnt, NP);

    readout_kernel<<<(NG * 32 + 255) / 256, 256, 0, stream>>>(ro_sum, ro_cnt, pclsf, ro_lin, cb2, NG);
    gnorm_apply_ro_kernel<<<64, 32, 0, stream>>>(ro_lin, cb2, rn_gf, rn_bf2, rn_af,
                                                 d_out, flag, ro_f, NG);

    // ---- mesh GAT layer 1 ----
    gemm_bf_kernel<32, 256, 4, 6, false><<<gTm, 256, 0, stream>>>(
        ro_f, Bm1, nullptr, nullptr, nullptr, nullptr, mal1f, mar1f, hm, elm, erm, NM);
    aggr4_kernel<4, 6, 256><<<tAm, 256, 0, stream>>>(hm, elm, erm, off_m, csr_m, gm, cb3,
                                                     wsctr + 2, tAm, NM, 0.01f);

    // ---- mesh GAT layer 2 ----
    gemm_bf_kernel<256, 96, 3, 5, true><<<gTm, 256, 0, stream>>>(
        gm, Bm2, cb3, mg1_gf, mg1_bf, mg1_af, mal2f, mar2f, hm, elm, erm, NM);
    aggr4_kernel<3, 5, 96><<<tAm, 256, 0, stream>>>(hm, elm, erm, off_m, csr_m, gm, cb4,
                                                    wsctr + 3, tAm, NM, 0.01f);

    // ---- mesh GAT layer 3 ----
    gemm_bf_kernel<96, 64, 2, 5, true><<<gTm, 256, 0, stream>>>(
        gm, Bm3, cb4, mg2_gf, mg2_bf, mg2_af, mal3f, mar3f, hm, elm, erm, NM);
    aggr_mean_kernel<<<gM2, 256, 0, stream>>>(hm, elm, erm, off_m, csr_m, nullptr,
                                              msum, nullptr, NM);
    final_kernel<<<1, 64, 0, stream>>>(msum, mclsf, d_out, flag, NM);

    (void)n_in; (void)out_size; (void)ws_size;
}

// Round 7
// 549.463 us; speedup vs baseline: 1.3670x; 1.3670x over previous
//
#include <hip/hip_runtime.h>

typedef unsigned short ushort;
typedef unsigned int uint;
typedef __attribute__((ext_vector_type(8))) short short8;
typedef __attribute__((ext_vector_type(4))) float float4v;

#define DEV __device__ __forceinline__

DEV float b2f(ushort u) {
    union { uint i; float f; } v; v.i = ((uint)u) << 16; return v.f;
}
DEV ushort f2b(float f) {
    union { float f; uint i; } v; v.f = f;
    uint x = v.i;
    uint r = x + 0x7fffu + ((x >> 16) & 1u);
    return (ushort)(r >> 16);
}
DEV float leaky(float x, float s) { return x >= 0.f ? x : s * x; }

DEV void gload16(const void* g, void* l) {
    __builtin_amdgcn_global_load_lds((const __attribute__((address_space(1))) void*)g,
                                     (__attribute__((address_space(3))) void*)l, 16, 0, 0);
}

// ---------------- convert (+local sniff, +zero slice, +flag write) ----------------
struct ConvArgs {
    const void* s[37];
    float* d[37];
    int n[37];
};

__global__ __launch_bounds__(256) void convert_kernel(ConvArgs a, const ushort* __restrict__ x0,
                                                      int* __restrict__ flag) {
    __shared__ int sfp32;
    int tid = threadIdx.x;
    if (tid < 64) {
        int cnt = 0;
        for (int j = 0; j < 8; j++) {
            ushort u = x0[(tid * 8 + j) * 2];
            int e = (u >> 7) & 0xFF;
            if (e >= 100 && e <= 140) cnt++;
        }
#pragma unroll
        for (int m = 1; m < 64; m <<= 1) cnt += __shfl_xor(cnt, m, 64);
        if (tid == 0) sfp32 = (cnt < 256) ? 1 : 0;
    }
    __syncthreads();
    bool fp32 = (sfp32 != 0);
    if (blockIdx.x == 0 && blockIdx.y == 0 && tid == 0) *flag = fp32 ? 1 : 0;

    int ai = blockIdx.y;
    int n = a.n[ai];
    const void* s = a.s[ai];
    float* d = a.d[ai];
    int stride = gridDim.x * blockDim.x;
    if (s == nullptr) {
        for (int i = blockIdx.x * blockDim.x + tid; i < n; i += stride) d[i] = 0.f;
    } else {
        for (int i = blockIdx.x * blockDim.x + tid; i < n; i += stride)
            d[i] = fp32 ? ((const float*)s)[i] : b2f(((const ushort*)s)[i]);
    }
}

// ---------------- pack weights to bf16 [K/8][N][8] + fold-in prep_elr (y==5) ----------------
struct PackArgs { const float* W; ushort* O; int K; int N; };
struct Pack5 {
    PackArgs m[5];
    const float *W1, *al1, *ar1;
    float *wal, *war;
};

__global__ __launch_bounds__(256) void pack5_kernel(Pack5 pa) {
    int mi = blockIdx.y;
    if (mi == 5) {
        // prep: wal[k][h] = sum_d W1[k][h*64+d]*al1[h][d]  (el/er linear in h)
        if (blockIdx.x == 0 && threadIdx.x < 20) {
            int t = threadIdx.x;
            int k = t >> 2, h = t & 3;
            float sl = 0.f, sr = 0.f;
            for (int d = 0; d < 64; d++) {
                float w = pa.W1[k * 256 + h * 64 + d];
                sl += w * pa.al1[h * 64 + d];
                sr += w * pa.ar1[h * 64 + d];
            }
            pa.wal[t] = sl;
            pa.war[t] = sr;
        }
        return;
    }
    const float* __restrict__ W = pa.m[mi].W;
    ushort* __restrict__ O = pa.m[mi].O;
    int K = pa.m[mi].K, N = pa.m[mi].N;
    int G = (K >> 3) * N;
    for (int gi = blockIdx.x * 256 + threadIdx.x; gi < G; gi += gridDim.x * 256) {
        int kb = gi / N;
        int n = gi - kb * N;
        const float* wp = W + (size_t)(kb * 8) * N + n;
        uint4 pk;
        pk.x = (uint)f2b(wp[0]) | ((uint)f2b(wp[N]) << 16);
        pk.y = (uint)f2b(wp[2 * N]) | ((uint)f2b(wp[3 * N]) << 16);
        pk.z = (uint)f2b(wp[4 * N]) | ((uint)f2b(wp[5 * N]) << 16);
        pk.w = (uint)f2b(wp[6 * N]) | ((uint)f2b(wp[7 * N]) << 16);
        *(uint4*)(O + (size_t)gi * 8) = pk;
    }
}

// ---------------- CSR build (patch+mesh merged) ----------------
__global__ __launch_bounds__(256) void hist_both(const int* __restrict__ dstP, int* __restrict__ cntP, int EPc,
                                                 const int* __restrict__ dstM, int* __restrict__ cntM, int EMc,
                                                 int PB) {
    bool patch = (int)blockIdx.x < PB;
    const int* dst = patch ? dstP : dstM;
    int* cnt = patch ? cntP : cntM;
    int E = patch ? EPc : EMc;
    int nb = patch ? PB : gridDim.x - PB;
    int b = patch ? blockIdx.x : blockIdx.x - PB;
    int stride = nb * blockDim.x;
    for (int i = b * blockDim.x + threadIdx.x; i < E; i += stride)
        atomicAdd(&cnt[dst[i]], 1);
}

__global__ __launch_bounds__(256) void scan_both(const int* __restrict__ cntP, int* __restrict__ offP,
                                                 int* __restrict__ bsumP, int nP, int SBP,
                                                 const int* __restrict__ cntM, int* __restrict__ offM,
                                                 int* __restrict__ bsumM, int nM) {
    __shared__ int ls[256];
    bool patch = (int)blockIdx.x < SBP;
    const int* cnt = patch ? cntP : cntM;
    int* off = patch ? offP : offM;
    int* bsum = patch ? bsumP : bsumM;
    int n = patch ? nP : nM;
    int b = patch ? blockIdx.x : blockIdx.x - SBP;
    int t = threadIdx.x;
    int base = b * 2048 + t * 8;
    int v[8];
    int s = 0;
#pragma unroll
    for (int i = 0; i < 8; i++) {
        int idx = base + i;
        v[i] = idx < n ? cnt[idx] : 0;
        s += v[i];
    }
    ls[t] = s;
    __syncthreads();
#pragma unroll
    for (int d = 1; d < 256; d <<= 1) {
        int add = (t >= d) ? ls[t - d] : 0;
        __syncthreads();
        ls[t] += add;
        __syncthreads();
    }
    int run = ls[t] - s;
#pragma unroll
    for (int i = 0; i < 8; i++) {
        int idx = base + i;
        if (idx < n) off[idx] = run;
        run += v[i];
    }
    if (t == 255) bsum[b] = ls[255];
}

__global__ __launch_bounds__(256) void fixup_both(const int* __restrict__ bsumP, int* __restrict__ offP,
                                                  int nP, int SBP,
                                                  const int* __restrict__ bsumM, int* __restrict__ offM,
                                                  int nM, int SBM) {
    bool patch = (int)blockIdx.x < SBP;
    const int* bsum = patch ? bsumP : bsumM;
    int* off = patch ? offP : offM;
    int n = patch ? nP : nM;
    int nb = patch ? SBP : SBM;
    int b = patch ? blockIdx.x : blockIdx.x - SBP;
    int t = threadIdx.x;
    int base = 0;
    for (int i = 0; i < b; i++) base += bsum[i];
    int idx0 = b * 2048 + t * 8;
    if (base != 0) {
#pragma unroll
        for (int i = 0; i < 8; i++) {
            int idx = idx0 + i;
            if (idx < n) off[idx] += base;
        }
    }
    if (b == nb - 1 && t == 255) off[n] = base + bsum[b];
}

__global__ __launch_bounds__(256) void scatter_both(const int* __restrict__ srcP, const int* __restrict__ dstP,
                                                    const int* __restrict__ offP, int* __restrict__ curP,
                                                    int* __restrict__ csrP, int EPc,
                                                    const int* __restrict__ srcM, const int* __restrict__ dstM,
                                                    const int* __restrict__ offM, int* __restrict__ curM,
                                                    int* __restrict__ csrM, int EMc, int PB) {
    bool patch = (int)blockIdx.x < PB;
    const int* src = patch ? srcP : srcM;
    const int* dst = patch ? dstP : dstM;
    const int* off = patch ? offP : offM;
    int* cursor = patch ? curP : curM;
    int* csr = patch ? csrP : csrM;
    int E = patch ? EPc : EMc;
    int nb = patch ? PB : gridDim.x - PB;
    int b = patch ? blockIdx.x : blockIdx.x - PB;
    int stride = nb * blockDim.x;
    for (int i = b * blockDim.x + threadIdx.x; i < E; i += stride) {
        int d = dst[i];
        int pos = off[d] + atomicAdd(&cursor[d], 1);
        csr[pos] = src[i];
    }
}

// ---------------- layer-1: el/er via precomputed 5x4 wal/war (one thread per node) ----------------
__global__ __launch_bounds__(256) void proj1b_kernel(const float* __restrict__ x,
                                                     const float* __restrict__ wal,
                                                     const float* __restrict__ war,
                                                     float* __restrict__ el,
                                                     float* __restrict__ er, int Nn) {
    int n = blockIdx.x * 256 + threadIdx.x;
    if (n >= Nn) return;
    float xv[5];
#pragma unroll
    for (int k = 0; k < 5; k++) xv[k] = x[n * 5 + k];
    float l0 = 0.f, l1 = 0.f, l2 = 0.f, l3 = 0.f;
    float r0 = 0.f, r1 = 0.f, r2 = 0.f, r3 = 0.f;
#pragma unroll
    for (int k = 0; k < 5; k++) {
        float xk = xv[k];
        l0 += xk * wal[k * 4 + 0];
        l1 += xk * wal[k * 4 + 1];
        l2 += xk * wal[k * 4 + 2];
        l3 += xk * wal[k * 4 + 3];
        r0 += xk * war[k * 4 + 0];
        r1 += xk * war[k * 4 + 1];
        r2 += xk * war[k * 4 + 2];
        r3 += xk * war[k * 4 + 3];
    }
    *(float4*)(el + n * 4) = make_float4(l0, l1, l2, l3);
    *(float4*)(er + n * 4) = make_float4(r0, r1, r2, r3);
}

// ---------------- patch layer-1 aggregation: grid-stride tiles, register colstats ----------------
__global__ __launch_bounds__(256, 4) void aggr1_fly_kernel(const float* __restrict__ x,
                                                           const float* __restrict__ W,
                                                           const float* __restrict__ el,
                                                           const float* __restrict__ er,
                                                           const int* __restrict__ off,
                                                           const int* __restrict__ csr,
                                                           float* __restrict__ out,
                                                           float* __restrict__ cstat,
                                                           int ntiles, int Nn) {
    __shared__ float s1m[4][256];
    __shared__ float s1q[4][256];
    int wid = threadIdx.x >> 6;
    int lane = threadIdx.x & 63;
    int grp = lane / 20;          // 0..3 (grp 3 idle for edge work)
    int gl = lane - grp * 20;
    int h_ = gl / 5, k_ = gl - h_ * 5;  // h_ 0..3, k_ 0..4
    int c0 = lane * 4;
    int myhead = lane >> 4;
    float w0[5], w1[5], w2[5], w3[5];
#pragma unroll
    for (int k = 0; k < 5; k++) {
        float4 wv = *(const float4*)(W + k * 256 + c0);
        w0[k] = wv.x; w1[k] = wv.y; w2[k] = wv.z; w3[k] = wv.w;
    }
    float ls0 = 0.f, ls1 = 0.f, ls2 = 0.f, ls3 = 0.f;
    float lq0 = 0.f, lq1 = 0.f, lq2 = 0.f, lq3 = 0.f;

    for (int tile = blockIdx.x; tile < ntiles; tile += gridDim.x) {
        int dbase = tile * 12 + wid * 3;
        int d = dbase + grp;
        bool accl = (grp < 3) && (d < Nn);
        int dd = accl ? d : 0;
        float erd = accl ? er[dd * 4 + h_] : 0.f;
        float acc = 0.f, sh = 0.f;
        int e = accl ? off[dd] : 0;
        int e1 = accl ? off[dd + 1] : 0;
#define A1_ACC(XV, EV)                                  \
    {                                                   \
        float e0_ = (EV) + erd;                         \
        e0_ = e0_ >= 0.f ? e0_ : 0.2f * e0_;            \
        float w_ = __expf(fminf(e0_, 80.f));            \
        acc += w_ * (XV);                               \
        sh += w_;                                       \
    }
        for (; e + 4 <= e1; e += 4) {
            int s0 = csr[e], s1 = csr[e + 1], s2 = csr[e + 2], s3 = csr[e + 3];
            float x0 = x[s0 * 5 + k_];
            float x1 = x[s1 * 5 + k_];
            float x2 = x[s2 * 5 + k_];
            float x3 = x[s3 * 5 + k_];
            float v0 = el[s0 * 4 + h_];
            float v1 = el[s1 * 4 + h_];
            float v2 = el[s2 * 4 + h_];
            float v3 = el[s3 * 4 + h_];
            A1_ACC(x0, v0) A1_ACC(x1, v1) A1_ACC(x2, v2) A1_ACC(x3, v3)
        }
        for (; e < e1; e++) {
            int s0 = csr[e];
            float x0 = x[s0 * 5 + k_];
            float v0 = el[s0 * 4 + h_];
            A1_ACC(x0, v0)
        }
#undef A1_ACC
        // epilogue: for each of the 3 dsts, broadcast acc[h][:] and project through W
#pragma unroll
        for (int g3 = 0; g3 < 3; g3++) {
            int dsto = dbase + g3;
            if (dsto >= Nn) break;  // wave-uniform
            float a_k[5];
#pragma unroll
            for (int k = 0; k < 5; k++) a_k[k] = __shfl(acc, g3 * 20 + myhead * 5 + k, 64);
            float s = __shfl(sh, g3 * 20 + myhead * 5, 64);
            float inv = 1.f / fmaxf(s, 1e-9f);
            float o0 = 0.f, o1 = 0.f, o2 = 0.f, o3 = 0.f;
#pragma unroll
            for (int k = 0; k < 5; k++) {
                o0 += a_k[k] * w0[k]; o1 += a_k[k] * w1[k];
                o2 += a_k[k] * w2[k]; o3 += a_k[k] * w3[k];
            }
            float4 o;
            o.x = leaky(o0 * inv, 0.01f);
            o.y = leaky(o1 * inv, 0.01f);
            o.z = leaky(o2 * inv, 0.01f);
            o.w = leaky(o3 * inv, 0.01f);
            *(float4*)(out + (size_t)dsto * 256 + c0) = o;
            ls0 += o.x; lq0 += o.x * o.x;
            ls1 += o.y; lq1 += o.y * o.y;
            ls2 += o.z; lq2 += o.z * o.z;
            ls3 += o.w; lq3 += o.w * o.w;
        }
    }
    // one stats flush per block: LDS reduce across waves -> 2 atomics per column
    *(float4*)&s1m[wid][c0] = make_float4(ls0, ls1, ls2, ls3);
    *(float4*)&s1q[wid][c0] = make_float4(lq0, lq1, lq2, lq3);
    __syncthreads();
    int tid = threadIdx.x;
    float ssv = 0.f, sqv = 0.f;
#pragma unroll
    for (int w8 = 0; w8 < 4; w8++) { ssv += s1m[w8][tid]; sqv += s1q[w8][tid]; }
    float* dst = cstat + (size_t)(blockIdx.x & 7) * 1024;
    atomicAdd(dst + tid, ssv);
    atomicAdd(dst + 512 + tid, sqv);
}

// ---------------- gather aggregation: grid-stride tiles, register colstats ----------------
template <int H, int LOGD, int HD>
__global__ __launch_bounds__(256, 4) void aggr4_kernel(const ushort* __restrict__ h,
                                                       const float* __restrict__ el,
                                                       const float* __restrict__ er,
                                                       const int* __restrict__ off,
                                                       const int* __restrict__ csr,
                                                       float* __restrict__ out,
                                                       float* __restrict__ cstat,
                                                       int ntiles, int Nn,
                                                       float oslope) {
    __shared__ float ssm[8][HD];
    __shared__ float ssq[8][HD];
    int wid = threadIdx.x >> 6;
    int lane = threadIdx.x & 63;
    int half = lane >> 5, hl = lane & 31;
    constexpr int NL = HD / 8;
    int myhead = (hl * 8) >> LOGD;
    float rs0 = 0.f, rs1 = 0.f, rs2 = 0.f, rs3 = 0.f;
    float rs4 = 0.f, rs5 = 0.f, rs6 = 0.f, rs7 = 0.f;
    float rq0 = 0.f, rq1 = 0.f, rq2 = 0.f, rq3 = 0.f;
    float rq4 = 0.f, rq5 = 0.f, rq6 = 0.f, rq7 = 0.f;

    for (int tile = blockIdx.x; tile < ntiles; tile += gridDim.x) {
        int d = tile * 8 + wid * 2 + half;
        bool valid = (hl < NL) && (d < Nn);
        int dd = valid ? d : 0;
        float erd = valid ? er[dd * H + myhead] : 0.f;
        float a0 = 0.f, a1 = 0.f, a2 = 0.f, a3 = 0.f;
        float a4 = 0.f, a5 = 0.f, a6 = 0.f, a7 = 0.f, s = 0.f;
        int e = valid ? off[dd] : 0;
        int e1 = valid ? off[dd + 1] : 0;
#define A8_ACC(EV, HR)                                      \
    {                                                       \
        float ev_ = (EV) + erd;                             \
        ev_ = ev_ >= 0.f ? ev_ : 0.2f * ev_;                \
        float w_ = __expf(fminf(ev_, 80.f));                \
        a0 += w_ * b2f((ushort)(HR).x);                     \
        a1 += w_ * b2f((ushort)((HR).x >> 16));             \
        a2 += w_ * b2f((ushort)(HR).y);                     \
        a3 += w_ * b2f((ushort)((HR).y >> 16));             \
        a4 += w_ * b2f((ushort)(HR).z);                     \
        a5 += w_ * b2f((ushort)((HR).z >> 16));             \
        a6 += w_ * b2f((ushort)(HR).w);                     \
        a7 += w_ * b2f((ushort)((HR).w >> 16));             \
        s += w_;                                            \
    }
#define A8_ACCM(OK, EV, HR)                                 \
    {                                                       \
        float ev_ = (EV) + erd;                             \
        ev_ = ev_ >= 0.f ? ev_ : 0.2f * ev_;                \
        float w_ = (OK) ? __expf(fminf(ev_, 80.f)) : 0.f;   \
        a0 += w_ * b2f((ushort)(HR).x);                     \
        a1 += w_ * b2f((ushort)((HR).x >> 16));             \
        a2 += w_ * b2f((ushort)(HR).y);                     \
        a3 += w_ * b2f((ushort)((HR).y >> 16));             \
        a4 += w_ * b2f((ushort)(HR).z);                     \
        a5 += w_ * b2f((ushort)((HR).z >> 16));             \
        a6 += w_ * b2f((ushort)(HR).w);                     \
        a7 += w_ * b2f((ushort)((HR).w >> 16));             \
        s += w_;                                            \
    }
        for (; e + 4 <= e1; e += 4) {
            int s0 = csr[e], s1 = csr[e + 1], s2 = csr[e + 2], s3 = csr[e + 3];
            float e0 = el[s0 * H + myhead];
            float e1v = el[s1 * H + myhead];
            float e2v = el[s2 * H + myhead];
            float e3v = el[s3 * H + myhead];
            uint4 h0 = *(const uint4*)(h + (size_t)s0 * HD + hl * 8);
            uint4 h1 = *(const uint4*)(h + (size_t)s1 * HD + hl * 8);
            uint4 h2 = *(const uint4*)(h + (size_t)s2 * HD + hl * 8);
            uint4 h3 = *(const uint4*)(h + (size_t)s3 * HD + hl * 8);
            A8_ACC(e0, h0) A8_ACC(e1v, h1) A8_ACC(e2v, h2) A8_ACC(e3v, h3)
        }
        if (e < e1) {
            bool k1 = e + 1 < e1, k2 = e + 2 < e1, k3 = e + 3 < e1;
            int s0 = csr[e];
            int s1 = csr[k1 ? e + 1 : e];
            int s2 = csr[k2 ? e + 2 : e];
            int s3 = csr[k3 ? e + 3 : e];
            float e0 = el[s0 * H + myhead];
            float e1v = el[s1 * H + myhead];
            float e2v = el[s2 * H + myhead];
            float e3v = el[s3 * H + myhead];
            uint4 h0 = *(const uint4*)(h + (size_t)s0 * HD + hl * 8);
            uint4 h1 = *(const uint4*)(h + (size_t)s1 * HD + hl * 8);
            uint4 h2 = *(const uint4*)(h + (size_t)s2 * HD + hl * 8);
            uint4 h3 = *(const uint4*)(h + (size_t)s3 * HD + hl * 8);
            A8_ACCM(true, e0, h0) A8_ACCM(k1, e1v, h1) A8_ACCM(k2, e2v, h2) A8_ACCM(k3, e3v, h3)
        }
#undef A8_ACC
#undef A8_ACCM
        if (valid) {
            float inv = 1.f / fmaxf(s, 1e-9f);
            float o0 = leaky(a0 * inv, oslope);
            float o1 = leaky(a1 * inv, oslope);
            float o2 = leaky(a2 * inv, oslope);
            float o3 = leaky(a3 * inv, oslope);
            float o4 = leaky(a4 * inv, oslope);
            float o5 = leaky(a5 * inv, oslope);
            float o6 = leaky(a6 * inv, oslope);
            float o7 = leaky(a7 * inv, oslope);
            float* po = out + (size_t)dd * HD + hl * 8;
            *(float4*)(po) = make_float4(o0, o1, o2, o3);
            *(float4*)(po + 4) = make_float4(o4, o5, o6, o7);
            rs0 += o0; rq0 += o0 * o0;
            rs1 += o1; rq1 += o1 * o1;
            rs2 += o2; rq2 += o2 * o2;
            rs3 += o3; rq3 += o3 * o3;
            rs4 += o4; rq4 += o4 * o4;
            rs5 += o5; rq5 += o5 * o5;
            rs6 += o6; rq6 += o6 * o6;
            rs7 += o7; rq7 += o7 * o7;
        }
    }
    // one stats flush per block
    int r = wid * 2 + half;
    if (hl < NL) {
        int cb = hl * 8;
        *(float4*)&ssm[r][cb] = make_float4(rs0, rs1, rs2, rs3);
        *(float4*)&ssm[r][cb + 4] = make_float4(rs4, rs5, rs6, rs7);
        *(float4*)&ssq[r][cb] = make_float4(rq0, rq1, rq2, rq3);
        *(float4*)&ssq[r][cb + 4] = make_float4(rq4, rq5, rq6, rq7);
    }
    __syncthreads();
    int tid = threadIdx.x;
    if (tid < HD) {
        float sv = 0.f, qv = 0.f;
#pragma unroll
        for (int rr = 0; rr < 8; rr++) { sv += ssm[rr][tid]; qv += ssq[rr][tid]; }
        float* dst = cstat + (size_t)(blockIdx.x & 7) * 1024;
        atomicAdd(dst + tid, sv);
        atomicAdd(dst + 512 + tid, qv);
    }
}

// final GAT layer: H=2, D=32, HD=64 — 2 dst/wave + block LDS pre-reduction before atomics
__global__ __launch_bounds__(256, 4) void aggr_mean_kernel(const ushort* __restrict__ h,
                                                           const float* __restrict__ el,
                                                           const float* __restrict__ er,
                                                           const int* __restrict__ off,
                                                           const int* __restrict__ csr,
                                                           const int* __restrict__ gid,
                                                           float* __restrict__ out_sum,
                                                           float* __restrict__ out_cnt,
                                                           int Nn) {
    __shared__ float red[8][32];
    __shared__ int gids[8];
    int wid = threadIdx.x >> 6;
    int lane = threadIdx.x & 63;
    int half = lane >> 5;
    int hl = lane & 31;
    int row = wid * 2 + half;
    int d = blockIdx.x * 8 + row;
    bool valid = d < Nn;
    int dd = valid ? d : 0;
    int head = hl >> 4;  // cols 2hl, 2hl+1; head1 when hl>=16
    float erd = er[dd * 2 + head];
    float a0 = 0.f, a1 = 0.f, s = 0.f;
    int e = valid ? off[dd] : 0;
    int e1 = valid ? off[dd + 1] : 0;
#define AM_ACC(Q, V)                                        \
    {                                                       \
        float ev_ = (head ? (Q).y : (Q).x) + erd;           \
        ev_ = ev_ >= 0.f ? ev_ : 0.2f * ev_;                \
        float w_ = __expf(fminf(ev_, 80.f));                \
        a0 += w_ * b2f((ushort)(V));                        \
        a1 += w_ * b2f((ushort)((V) >> 16));                \
        s += w_;                                            \
    }
#define AM_ACCM(OK, Q, V)                                   \
    {                                                       \
        float ev_ = (head ? (Q).y : (Q).x) + erd;           \
        ev_ = ev_ >= 0.f ? ev_ : 0.2f * ev_;                \
        float w_ = (OK) ? __expf(fminf(ev_, 80.f)) : 0.f;   \
        a0 += w_ * b2f((ushort)(V));                        \
        a1 += w_ * b2f((ushort)((V) >> 16));                \
        s += w_;                                            \
    }
    for (; e + 8 <= e1; e += 8) {
        int s0 = csr[e], s1 = csr[e + 1], s2 = csr[e + 2], s3 = csr[e + 3];
        int s4 = csr[e + 4], s5 = csr[e + 5], s6 = csr[e + 6], s7 = csr[e + 7];
        float2 q0 = *(const float2*)(el + s0 * 2);
        float2 q1 = *(const float2*)(el + s1 * 2);
        float2 q2 = *(const float2*)(el + s2 * 2);
        float2 q3 = *(const float2*)(el + s3 * 2);
        float2 q4 = *(const float2*)(el + s4 * 2);
        float2 q5 = *(const float2*)(el + s5 * 2);
        float2 q6 = *(const float2*)(el + s6 * 2);
        float2 q7 = *(const float2*)(el + s7 * 2);
        uint v0 = *(const uint*)(h + (size_t)s0 * 64 + hl * 2);
        uint v1 = *(const uint*)(h + (size_t)s1 * 64 + hl * 2);
        uint v2 = *(const uint*)(h + (size_t)s2 * 64 + hl * 2);
        uint v3 = *(const uint*)(h + (size_t)s3 * 64 + hl * 2);
        uint v4 = *(const uint*)(h + (size_t)s4 * 64 + hl * 2);
        uint v5 = *(const uint*)(h + (size_t)s5 * 64 + hl * 2);
        uint v6 = *(const uint*)(h + (size_t)s6 * 64 + hl * 2);
        uint v7 = *(const uint*)(h + (size_t)s7 * 64 + hl * 2);
        AM_ACC(q0, v0) AM_ACC(q1, v1) AM_ACC(q2, v2) AM_ACC(q3, v3)
        AM_ACC(q4, v4) AM_ACC(q5, v5) AM_ACC(q6, v6) AM_ACC(q7, v7)
    }
    if (e < e1) {
        bool k1 = e + 1 < e1, k2 = e + 2 < e1, k3 = e + 3 < e1;
        bool k4 = e + 4 < e1, k5 = e + 5 < e1, k6 = e + 6 < e1, k7 = e + 7 < e1;
        int s0 = csr[e];
        int s1 = csr[k1 ? e + 1 : e];
        int s2 = csr[k2 ? e + 2 : e];
        int s3 = csr[k3 ? e + 3 : e];
        int s4 = csr[k4 ? e + 4 : e];
        int s5 = csr[k5 ? e + 5 : e];
        int s6 = csr[k6 ? e + 6 : e];
        int s7 = csr[k7 ? e + 7 : e];
        float2 q0 = *(const float2*)(el + s0 * 2);
        float2 q1 = *(const float2*)(el + s1 * 2);
        float2 q2 = *(const float2*)(el + s2 * 2);
        float2 q3 = *(const float2*)(el + s3 * 2);
        float2 q4 = *(const float2*)(el + s4 * 2);
        float2 q5 = *(const float2*)(el + s5 * 2);
        float2 q6 = *(const float2*)(el + s6 * 2);
        float2 q7 = *(const float2*)(el + s7 * 2);
        uint v0 = *(const uint*)(h + (size_t)s0 * 64 + hl * 2);
        uint v1 = *(const uint*)(h + (size_t)s1 * 64 + hl * 2);
        uint v2 = *(const uint*)(h + (size_t)s2 * 64 + hl * 2);
        uint v3 = *(const uint*)(h + (size_t)s3 * 64 + hl * 2);
        uint v4 = *(const uint*)(h + (size_t)s4 * 64 + hl * 2);
        uint v5 = *(const uint*)(h + (size_t)s5 * 64 + hl * 2);
        uint v6 = *(const uint*)(h + (size_t)s6 * 64 + hl * 2);
        uint v7 = *(const uint*)(h + (size_t)s7 * 64 + hl * 2);
        AM_ACCM(true, q0, v0) AM_ACCM(k1, q1, v1) AM_ACCM(k2, q2, v2) AM_ACCM(k3, q3, v3)
        AM_ACCM(k4, q4, v4) AM_ACCM(k5, q5, v5) AM_ACCM(k6, q6, v6) AM_ACCM(k7, q7, v7)
    }
#undef AM_ACC
#undef AM_ACCM
    float inv = 1.f / fmaxf(s, 1e-9f);
    float y0 = a0 * inv, y1 = a1 * inv;
    // head-mean: col c pairs with c+32 -> lane hl+16 within same half
    float p0 = __shfl(y0, lane + 16, 64);
    float p1 = __shfl(y1, lane + 16, 64);
    if (hl < 16) {
        red[row][2 * hl] = valid ? 0.5f * (y0 + p0) : 0.f;
        red[row][2 * hl + 1] = valid ? 0.5f * (y1 + p1) : 0.f;
        if (hl == 0) gids[row] = valid ? (gid ? gid[d] : 0) : -1;
    }
    __syncthreads();
    // block-level reduction over runs of equal gid -> few device atomics
    if (threadIdx.x < 32) {
        int c = threadIdx.x;
        float sum = 0.f;
        int cur = gids[0];
#pragma unroll
        for (int r = 0; r < 8; r++) {
            int gr = gids[r];
            if (gr != cur) {
                if (cur >= 0) atomicAdd(&out_sum[cur * 32 + c], sum);
                sum = 0.f;
                cur = gr;
            }
            if (gr >= 0) sum += red[r][c];
        }
        if (cur >= 0) atomicAdd(&out_sum[cur * 32 + c], sum);
    } else if (threadIdx.x == 32 && out_cnt) {
        float cnt = 0.f;
        int cur = gids[0];
#pragma unroll
        for (int r = 0; r < 8; r++) {
            int gr = gids[r];
            if (gr != cur) {
                if (cur >= 0) atomicAdd(&out_cnt[cur], cnt);
                cnt = 0.f;
                cur = gr;
            }
            if (gr >= 0) cnt += 1.f;
        }
        if (cur >= 0) atomicAdd(&out_cnt[cur], cnt);
    }
}

// GraphNorm apply for readout: writes d_out (per flag) + fp32 mesh input (8-copy stats)
__global__ void gnorm_apply_ro_kernel(const float* __restrict__ x,
                                      const float* __restrict__ cstat,
                                      const float* __restrict__ g,
                                      const float* __restrict__ b,
                                      const float* __restrict__ a,
                                      void* __restrict__ doutv,
                                      const int* __restrict__ flag,
                                      float* __restrict__ rof, int Nn) {
    int c = threadIdx.x;  // C = 32
    float cs = 0.f, cq = 0.f;
#pragma unroll
    for (int s8 = 0; s8 < 8; s8++) {
        cs += cstat[s8 * 1024 + c];
        cq += cstat[s8 * 1024 + 512 + c];
    }
    float invn = 1.f / (float)Nn;
    float mu = cs * invn, ex2 = cq * invn;
    float av = a[c];
    float var = ex2 - 2.f * av * mu * mu + av * av * mu * mu;
    float sc = g[c] * rsqrtf(var + 1e-5f);
    float sh = b[c] - sc * av * mu;
    bool fp32 = (*flag != 0);
    for (int r = blockIdx.x; r < Nn; r += gridDim.x) {
        int i = r * 32 + c;
        float v = x[i] * sc + sh;
        rof[i] = v;
        if (fp32) ((float*)doutv)[15 + i] = v;
        else      ((ushort*)doutv)[15 + i] = f2b(v);
    }
}

// ---------------- readout: segment-mean @ pcls + leaky (fp32 out, fused colstats) ----------------
__global__ __launch_bounds__(256) void readout_kernel(const float* __restrict__ ro_sum,
                                                      const float* __restrict__ ro_cnt,
                                                      const float* __restrict__ pcls,
                                                      float* __restrict__ ro_lin,
                                                      float* __restrict__ cstat, int NGc) {
    __shared__ float ss[32], sq[32];
    int tid = threadIdx.x;
    if (tid < 32) { ss[tid] = 0.f; sq[tid] = 0.f; }
    __syncthreads();
    int idx = blockIdx.x * 256 + tid;
    int g = idx >> 5, c = idx & 31;
    float v = 0.f;
    if (g < NGc) {
        float inv = 1.f / fmaxf(ro_cnt[g], 1.f);
        float acc = 0.f;
#pragma unroll
        for (int k = 0; k < 32; k++) acc += ro_sum[g * 32 + k] * inv * pcls[k * 32 + c];
        v = leaky(acc, 0.01f);
        ro_lin[g * 32 + c] = v;
    }
    atomicAdd(&ss[c], v);
    atomicAdd(&sq[c], v * v);
    __syncthreads();
    if (tid < 32) {
        float* dst = cstat + (size_t)(blockIdx.x & 7) * 1024;
        atomicAdd(dst + tid, ss[tid]);
        atomicAdd(dst + 512 + tid, sq[tid]);
    }
}

// ---------------- MFMA GEMM v2: C(bf16) = gnorm(A:fp32) @ B'(bf16 prepacked), fused el/er ----------------
template <int K, int N, int H, int LOGD, bool GN>
__global__ __launch_bounds__(256, 4) void gemm_bf_kernel(const float* __restrict__ A,
                                                         const ushort* __restrict__ Bc,
                                                         const float* __restrict__ csum,
                                                         const float* __restrict__ g,
                                                         const float* __restrict__ gb,
                                                         const float* __restrict__ ga,
                                                         const float* __restrict__ al,
                                                         const float* __restrict__ ar,
                                                         ushort* __restrict__ C,
                                                         float* __restrict__ el,
                                                         float* __restrict__ er, int M) {
    constexpr int NT = N / 16;
    constexpr int T = K / 32;
    constexpr int BG = 4 * N;             // B 16B-granules per 32-K chunk
    constexpr int RB = (BG + 255) / 256;  // staging rounds for B
    __shared__ __align__(16) ushort Blds[2][BG * 8];
    __shared__ float ScL[K], ShL[K];
    int tid = threadIdx.x;
    int w = tid >> 6, lane = tid & 63, q = lane >> 4, l16 = lane & 15;
    int m0 = blockIdx.x * 64;
    if constexpr (GN) {
        if (tid < K) {
            float cs = 0.f, cq = 0.f;
#pragma unroll
            for (int s8 = 0; s8 < 8; s8++) {
                cs += csum[s8 * 1024 + tid];
                cq += csum[s8 * 1024 + 512 + tid];
            }
            float invn = 1.f / (float)M;
            float mu = cs * invn, ex2 = cq * invn;
            float av = ga[tid];
            float var = ex2 - 2.f * av * mu * mu + av * av * mu * mu;
            float sc = g[tid] * rsqrtf(var + 1e-5f);
            ScL[tid] = sc;
            ShL[tid] = gb[tid] - sc * av * mu;
        }
    }
    int row = m0 + w * 16 + l16;
    const float* ap = A + (size_t)(row < M ? row : 0) * K + q * 8;

    // prologue: stage B chunk 0; preload A regs chunk 0
#pragma unroll
    for (int rb = 0; rb < RB; rb++) {
        int gidx = rb * 256 + tid;
        if (BG % 256 == 0 || gidx < BG) gload16(Bc + (size_t)gidx * 8, &Blds[0][gidx * 8]);
    }
    float4 a0 = *(const float4*)(ap);
    float4 a1 = *(const float4*)(ap + 4);
    float4v acc[NT];
#pragma unroll
    for (int nt = 0; nt < NT; nt++) acc[nt] = (float4v){0.f, 0.f, 0.f, 0.f};
    __syncthreads();  // B chunk 0 resident (+ ScL/ShL visible)

    int cur = 0;
    for (int t = 0; t < T; t++) {
        float4 n0, n1;
        bool more = (t + 1 < T);
        if (more) {
#pragma unroll
            for (int rb = 0; rb < RB; rb++) {
                int gidx = rb * 256 + tid;
                if (BG % 256 == 0 || gidx < BG)
                    gload16(Bc + (size_t)((t + 1) * BG + gidx) * 8, &Blds[cur ^ 1][gidx * 8]);
            }
            n0 = *(const float4*)(ap + (t + 1) * 32);
            n1 = *(const float4*)(ap + (t + 1) * 32 + 4);
        }
        // gnorm + pack current A fragment
        if constexpr (GN) {
            int kc = t * 32 + q * 8;
            float4 sc0 = *(const float4*)(&ScL[kc]);
            float4 sc1 = *(const float4*)(&ScL[kc + 4]);
            float4 sh0 = *(const float4*)(&ShL[kc]);
            float4 sh1 = *(const float4*)(&ShL[kc + 4]);
            a0.x = a0.x * sc0.x + sh0.x;
            a0.y = a0.y * sc0.y + sh0.y;
            a0.z = a0.z * sc0.z + sh0.z;
            a0.w = a0.w * sc0.w + sh0.w;
            a1.x = a1.x * sc1.x + sh1.x;
            a1.y = a1.y * sc1.y + sh1.y;
            a1.z = a1.z * sc1.z + sh1.z;
            a1.w = a1.w * sc1.w + sh1.w;
        }
        union { uint4 u; short8 s; } cvt;
        cvt.u.x = (uint)f2b(a0.x) | ((uint)f2b(a0.y) << 16);
        cvt.u.y = (uint)f2b(a0.z) | ((uint)f2b(a0.w) << 16);
        cvt.u.z = (uint)f2b(a1.x) | ((uint)f2b(a1.y) << 16);
        cvt.u.w = (uint)f2b(a1.z) | ((uint)f2b(a1.w) << 16);
        short8 av = cvt.s;
#pragma unroll
        for (int nt = 0; nt < NT; nt++) {
            short8 bv = *(const short8*)(&Blds[cur][(q * N + nt * 16 + l16) * 8]);
            acc[nt] = __builtin_amdgcn_mfma_f32_16x16x32_bf16(av, bv, acc[nt], 0, 0, 0);
        }
        __syncthreads();  // drains prefetch vmcnt; releases buf[cur]
        if (more) { a0 = n0; a1 = n1; }
        cur ^= 1;
    }
    // epilogue: C store (bf16) + fused el/er
    float pel[4][H], per[4][H];
#pragma unroll
    for (int i = 0; i < 4; i++)
#pragma unroll
        for (int hh = 0; hh < H; hh++) { pel[i][hh] = 0.f; per[i][hh] = 0.f; }
#pragma unroll
    for (int nt = 0; nt < NT; nt++) {
        int col = nt * 16 + l16;
        float alc = al[col], arc = ar[col];
        constexpr int HSH = LOGD - 4;
        int hh = nt >> HSH;
#pragma unroll
        for (int i = 0; i < 4; i++) {
            int orow = m0 + w * 16 + q * 4 + i;
            float v = acc[nt][i];
            if (orow < M) C[(size_t)orow * N + col] = f2b(v);
            pel[i][hh] += v * alc;
            per[i][hh] += v * arc;
        }
    }
#pragma unroll
    for (int i = 0; i < 4; i++) {
#pragma unroll
        for (int hh = 0; hh < H; hh++) {
            float vl = pel[i][hh], vr = per[i][hh];
#pragma unroll
            for (int m = 1; m < 16; m <<= 1) {
                vl += __shfl_xor(vl, m, 64);
                vr += __shfl_xor(vr, m, 64);
            }
            if (l16 == 0) {
                int orow = m0 + w * 16 + q * 4 + i;
                if (orow < M) { el[orow * H + hh] = vl; er[orow * H + hh] = vr; }
            }
        }
    }
}

// ---------------- final: node-mean @ mcls ----------------
__global__ __launch_bounds__(64) void final_kernel(const float* __restrict__ msum,
                                                   const float* __restrict__ mcls,
                                                   void* __restrict__ doutv,
                                                   const int* __restrict__ flag, int Nm) {
    int t = threadIdx.x;
    if (t < 15) {
        float inv = 1.f / (float)Nm;
        float acc = 0.f;
#pragma unroll
        for (int c = 0; c < 32; c++) acc += msum[c] * inv * mcls[c * 15 + t];
        if (*flag) ((float*)doutv)[t] = acc;
        else       ((ushort*)doutv)[t] = f2b(acc);
    }
}

extern "C" void kernel_launch(void* const* d_in, const int* in_sizes, int n_in,
                              void* d_out, int out_size, void* d_ws, size_t ws_size,
                              hipStream_t stream) {
    const int NP = 100000, NG = 2000, EP = 800000, NM = 2000, EM = 32000;

    const int* patch_src = (const int*)d_in[1];
    const int* patch_dst = (const int*)d_in[2];
    const int* patch_gid = (const int*)d_in[3];
    const int* mesh_src = (const int*)d_in[4];
    const int* mesh_dst = (const int*)d_in[5];

    char* p = (char*)d_ws;
    auto alloc = [&](size_t bytes) -> char* {
        char* r = p;
        p += (bytes + 255) & ~(size_t)255;
        return r;
    };
    char* zbase = p;
    int* cnt_p = (int*)alloc((size_t)NP * 4);
    int* cursor_p = (int*)alloc((size_t)NP * 4);
    int* cnt_m = (int*)alloc((size_t)NM * 4);
    int* cursor_m = (int*)alloc((size_t)NM * 4);
    float* ro_sum = (float*)alloc((size_t)NG * 32 * 4);
    float* ro_cnt = (float*)alloc((size_t)NG * 4);
    float* msum = (float*)alloc(32 * 4);
    float* colbuf = (float*)alloc((size_t)5 * 8 * 1024 * 4);  // stat buffers x 8 copies x (512 sum + 512 sq)
    size_t zbytes = (size_t)(p - zbase);
    int* flag = (int*)alloc(256);
    int* off_p = (int*)alloc((size_t)(NP + 1) * 4);
    int* off_m = (int*)alloc((size_t)(NM + 1) * 4);
    int* bsum_p = (int*)alloc(64 * 4);
    int* bsum_m = (int*)alloc(16 * 4);
    int* csr_p = (int*)alloc((size_t)EP * 4);
    int* csr_m = (int*)alloc((size_t)EM * 4);
    float* el = (float*)alloc((size_t)NP * 4 * 4);
    float* er = (float*)alloc((size_t)NP * 4 * 4);
    ushort* hbuf = (ushort*)alloc((size_t)NP * 256 * 2);   // bf16 gemm-output gather buffer
    float* gbuf = (float*)alloc((size_t)NP * 256 * 4);     // fp32 aggr output (gemm A input)
    ushort* hm = (ushort*)alloc((size_t)NM * 256 * 2);
    float* gm = (float*)alloc((size_t)NM * 256 * 4);
    float* elm = (float*)alloc((size_t)NM * 4 * 4);
    float* erm = (float*)alloc((size_t)NM * 4 * 4);
    float* ro_lin = (float*)alloc((size_t)NG * 32 * 4);
    float* ro_f = (float*)alloc((size_t)NG * 32 * 4);
    // prepacked bf16 weights [K/8][N][8]
    ushort* Bp2 = (ushort*)alloc(256 * 192 * 2);
    ushort* Bp3 = (ushort*)alloc(192 * 64 * 2);
    ushort* Bm1 = (ushort*)alloc(32 * 256 * 2);
    ushort* Bm2 = (ushort*)alloc(256 * 96 * 2);
    ushort* Bm3 = (ushort*)alloc(96 * 64 * 2);
    float* wal1 = (float*)alloc(20 * 4);
    float* war1 = (float*)alloc(20 * 4);

    ConvArgs ca;
    float* convp[36];
    int conv_idx[36];
    conv_idx[0] = 0;
    for (int i = 1; i < 36; i++) conv_idx[i] = 5 + i;
    for (int j = 0; j < 36; j++) {
        int ii = conv_idx[j];
        int n = in_sizes[ii];
        float* dd = (float*)alloc((size_t)n * 4);
        ca.s[j] = d_in[ii];
        ca.d[j] = dd;
        ca.n[j] = n;
        convp[j] = dd;
    }
    ca.s[36] = nullptr;
    ca.d[36] = (float*)zbase;
    ca.n[36] = (int)(zbytes / 4);

    const float* xf = convp[0];
    const float *pW1f = convp[1], *pal1f = convp[2], *par1f = convp[3];
    const float *pg1_gf = convp[4], *pg1_bf = convp[5], *pg1_af = convp[6];
    const float *pW2f = convp[7], *pal2f = convp[8], *par2f = convp[9];
    const float *pg2_gf = convp[10], *pg2_bf = convp[11], *pg2_af = convp[12];
    const float *pW3f = convp[13], *pal3f = convp[14], *par3f = convp[15];
    const float* pclsf = convp[16];
    const float *rn_gf = convp[17], *rn_bf2 = convp[18], *rn_af = convp[19];
    const float *mW1f = convp[20], *mal1f = convp[21], *mar1f = convp[22];
    const float *mg1_gf = convp[23], *mg1_bf = convp[24], *mg1_af = convp[25];
    const float *mW2f = convp[26], *mal2f = convp[27], *mar2f = convp[28];
    const float *mg2_gf = convp[29], *mg2_bf = convp[30], *mg2_af = convp[31];
    const float *mW3f = convp[32], *mal3f = convp[33], *mar3f = convp[34];
    const float* mclsf = convp[35];

    convert_kernel<<<dim3(16, 37), 256, 0, stream>>>(ca, (const ushort*)d_in[0], flag);

    // pack all 5 GEMM weight matrices to bf16 + prep wal/war (y==5 row)
    Pack5 p5;
    p5.m[0] = {pW2f, Bp2, 256, 192};
    p5.m[1] = {pW3f, Bp3, 192, 64};
    p5.m[2] = {mW1f, Bm1, 32, 256};
    p5.m[3] = {mW2f, Bm2, 256, 96};
    p5.m[4] = {mW3f, Bm3, 96, 64};
    p5.W1 = pW1f; p5.al1 = pal1f; p5.ar1 = par1f;
    p5.wal = wal1; p5.war = war1;
    pack5_kernel<<<dim3(48, 6), 256, 0, stream>>>(p5);

    const int SBP = (NP + 2047) / 2048, SBM = (NM + 2047) / 2048;
    hist_both<<<512 + 64, 256, 0, stream>>>(patch_dst, cnt_p, EP, mesh_dst, cnt_m, EM, 512);
    scan_both<<<SBP + SBM, 256, 0, stream>>>(cnt_p, off_p, bsum_p, NP, SBP, cnt_m, off_m, bsum_m, NM);
    fixup_both<<<SBP + SBM, 256, 0, stream>>>(bsum_p, off_p, NP, SBP, bsum_m, off_m, NM, SBM);
    scatter_both<<<512 + 64, 256, 0, stream>>>(patch_src, patch_dst, off_p, cursor_p, csr_p, EP,
                                               mesh_src, mesh_dst, off_m, cursor_m, csr_m, EM, 512);

    // grids: keep a queue of ~2x resident blocks per CU so completion-replacement
    // streaming hides per-block length variance (R5's 2048 == resident capacity
    // left CUs idle at the tail; R6's atomic work-steal serialized cross-XCD)
    int t1 = (NP + 11) / 12;            // aggr1 tiles
    int g1 = t1 < 4096 ? t1 : 4096;
    int tA = (NP + 7) / 8;              // aggr4 patch tiles
    int gA = tA < 4096 ? tA : 4096;
    int tAm = (NM + 7) / 8;             // aggr4 mesh tiles
    int gP2 = (NP + 7) / 8, gM2 = (NM + 7) / 8;
    int gT = (NP + 63) / 64, gTm = (NM + 63) / 64;
    float* cb0 = colbuf + 0 * 8192;
    float* cb1 = colbuf + 1 * 8192;
    float* cb2 = colbuf + 2 * 8192;
    float* cb3 = colbuf + 3 * 8192;
    float* cb4 = colbuf + 4 * 8192;

    // ---- patch GAT layer 1 ----
    proj1b_kernel<<<(NP + 255) / 256, 256, 0, stream>>>(xf, wal1, war1, el, er, NP);
    aggr1_fly_kernel<<<g1, 256, 0, stream>>>(xf, pW1f, el, er, off_p, csr_p, gbuf, cb0, t1, NP);

    // ---- patch GAT layer 2 ----
    gemm_bf_kernel<256, 192, 3, 6, true><<<gT, 256, 0, stream>>>(
        gbuf, Bp2, cb0, pg1_gf, pg1_bf, pg1_af, pal2f, par2f, hbuf, el, er, NP);
    aggr4_kernel<3, 6, 192><<<gA, 256, 0, stream>>>(hbuf, el, er, off_p, csr_p, gbuf, cb1, tA, NP, 0.01f);

    // ---- patch GAT layer 3 + readout ----
    gemm_bf_kernel<192, 64, 2, 5, true><<<gT, 256, 0, stream>>>(
        gbuf, Bp3, cb1, pg2_gf, pg2_bf, pg2_af, pal3f, par3f, hbuf, el, er, NP);
    aggr_mean_kernel<<<gP2, 256, 0, stream>>>(hbuf, el, er, off_p, csr_p, patch_gid,
                                              ro_sum, ro_cnt, NP);

    readout_kernel<<<(NG * 32 + 255) / 256, 256, 0, stream>>>(ro_sum, ro_cnt, pclsf, ro_lin, cb2, NG);
    gnorm_apply_ro_kernel<<<64, 32, 0, stream>>>(ro_lin, cb2, rn_gf, rn_bf2, rn_af,
                                                 d_out, flag, ro_f, NG);

    // ---- mesh GAT layer 1 ----
    gemm_bf_kernel<32, 256, 4, 6, false><<<gTm, 256, 0, stream>>>(
        ro_f, Bm1, nullptr, nullptr, nullptr, nullptr, mal1f, mar1f, hm, elm, erm, NM);
    aggr4_kernel<4, 6, 256><<<tAm, 256, 0, stream>>>(hm, elm, erm, off_m, csr_m, gm, cb3, tAm, NM, 0.01f);

    // ---- mesh GAT layer 2 ----
    gemm_bf_kernel<256, 96, 3, 5, true><<<gTm, 256, 0, stream>>>(
        gm, Bm2, cb3, mg1_gf, mg1_bf, mg1_af, mal2f, mar2f, hm, elm, erm, NM);
    aggr4_kernel<3, 5, 96><<<tAm, 256, 0, stream>>>(hm, elm, erm, off_m, csr_m, gm, cb4, tAm, NM, 0.01f);

    // ---- mesh GAT layer 3 ----
    gemm_bf_kernel<96, 64, 2, 5, true><<<gTm, 256, 0, stream>>>(
        gm, Bm3, cb4, mg2_gf, mg2_bf, mg2_af, mal3f, mar3f, hm, elm, erm, NM);
    aggr_mean_kernel<<<gM2, 256, 0, stream>>>(hm, elm, erm, off_m, csr_m, nullptr,
                                              msum, nullptr, NM);
    final_kernel<<<1, 64, 0, stream>>>(msum, mclsf, d_out, flag, NM);

    (void)n_in; (void)out_size; (void)ws_size;
}